// Round 2
// baseline (1958.052 us; speedup 1.0000x reference)
//
#include <hip/hip_runtime.h>
#include <hip/hip_bf16.h>

constexpr int BATCH = 4;
constexpr int SEQ   = 1024;
constexpr int DM    = 512;     // model dim = HEADS*HDIM
constexpr int NH    = 8;
constexpr int HD    = 64;
constexpr int NPOS  = 1025;    // 2*MAX_PEMB+1
constexpr int QT    = 4;       // queries per attention block (LDS < 64 KB)

// ---------------------------------------------------------------------------
// Tiled GEMM fp32: C[M,N] = A[M,K] @ B[K,N] (+ bias if non-null)
// tile 64x64, BK=16, 256 threads, 4x4 per thread
// ---------------------------------------------------------------------------
__global__ __launch_bounds__(256)
void gemm_f32(const float* __restrict__ A, const float* __restrict__ Bm,
              const float* __restrict__ bias, float* __restrict__ C,
              int M, int N, int K) {
    __shared__ float As[64][17];
    __shared__ float Bs[16][65];
    const int tid = threadIdx.x;
    const int tx = tid & 15, ty = tid >> 4;
    const int bm = blockIdx.y * 64, bn = blockIdx.x * 64;
    float acc[4][4] = {};
    for (int k0 = 0; k0 < K; k0 += 16) {
        #pragma unroll
        for (int i = 0; i < 4; i++) {
            int e = tid * 4 + i;           // 0..1023
            int r = e >> 4, c = e & 15;
            As[r][c] = A[(size_t)(bm + r) * K + k0 + c];
        }
        #pragma unroll
        for (int i = 0; i < 4; i++) {
            int e = tid * 4 + i;
            int r = e >> 6, c = e & 63;
            Bs[r][c] = Bm[(size_t)(k0 + r) * N + bn + c];
        }
        __syncthreads();
        #pragma unroll
        for (int kk = 0; kk < 16; kk++) {
            float a[4], b[4];
            #pragma unroll
            for (int i = 0; i < 4; i++) a[i] = As[ty * 4 + i][kk];
            #pragma unroll
            for (int j = 0; j < 4; j++) b[j] = Bs[kk][tx * 4 + j];
            #pragma unroll
            for (int i = 0; i < 4; i++)
                #pragma unroll
                for (int j = 0; j < 4; j++) acc[i][j] += a[i] * b[j];
        }
        __syncthreads();
    }
    #pragma unroll
    for (int i = 0; i < 4; i++)
        #pragma unroll
        for (int j = 0; j < 4; j++) {
            float bj = bias ? bias[bn + tx * 4 + j] : 0.f;
            C[(size_t)(bm + ty * 4 + i) * N + bn + tx * 4 + j] = acc[i][j] + bj;
        }
}

// ---------------------------------------------------------------------------
// Fused attention: per block = (b,h, QT query rows), 256 threads = 4 waves,
// wave w owns query row w (lane = 0..63).
//   phase 1: qp[row][j] = (scale*q_row) . pemb[j]   for all j in [0,1025)
//   phase 2: sc[row][t] = (scale*q_row) . k_t + qp[row][clip(s-t)+512]
//   phase 3: softmax per row
//   phase 4: ctx[row][d] = sum_t p[t] * v[t][d]
// ---------------------------------------------------------------------------
__global__ __launch_bounds__(256)
void attn_kernel(const float* __restrict__ qbuf, const float* __restrict__ kvbuf,
                 const float* __restrict__ pemb, float* __restrict__ ctxbuf) {
    __shared__ float sc[QT][SEQ];        // 16 KB scores
    __shared__ float qp[QT][NPOS + 3];   // 16.4 KB pos-attn table
    __shared__ float stg[64][68];        // 17.4 KB staging (pemb / k / v tiles)
    __shared__ float rowinv[QT];

    const int tid  = threadIdx.x;
    const int row  = tid >> 6;           // 0..3
    const int lane = tid & 63;
    const int bh   = blockIdx.y;
    const int b    = bh >> 3, h = bh & 7;
    const int s0   = blockIdx.x * QT;
    const int s    = s0 + row;
    const float scale = 0.125f;          // 64^-0.5

    // q row -> registers, pre-scaled
    float qreg[64];
    {
        const float* qrow = qbuf + (size_t)(b * SEQ + s) * DM + h * HD;
        #pragma unroll
        for (int d = 0; d < 64; d++) qreg[d] = qrow[d] * scale;
    }

    // ---- phase 1: qp table ----
    for (int jt = 0; jt < NPOS; jt += 64) {
        const int w = min(64, NPOS - jt);
        for (int e = tid; e < w * 64; e += 256) {
            int r = e >> 6, c = e & 63;
            stg[r][c] = pemb[(size_t)(jt + r) * 64 + c];
        }
        __syncthreads();
        if (lane < w) {
            const float* sp = stg[lane];
            float acc = 0.f;
            #pragma unroll
            for (int dv = 0; dv < 16; dv++) {
                float4 p4 = *(const float4*)(sp + dv * 4);
                acc += qreg[dv * 4 + 0] * p4.x + qreg[dv * 4 + 1] * p4.y
                     + qreg[dv * 4 + 2] * p4.z + qreg[dv * 4 + 3] * p4.w;
            }
            qp[row][jt + lane] = acc;
        }
        __syncthreads();
    }

    // ---- phase 2: scores ----
    for (int t0 = 0; t0 < SEQ; t0 += 64) {
        for (int e = tid; e < 64 * 64; e += 256) {
            int r = e >> 6, c = e & 63;
            stg[r][c] = kvbuf[(size_t)(b * SEQ + t0 + r) * 1024 + h * HD + c];
        }
        __syncthreads();
        {
            const int t = t0 + lane;
            const float* kp = stg[lane];
            float acc = 0.f;
            #pragma unroll
            for (int dv = 0; dv < 16; dv++) {
                float4 k4 = *(const float4*)(kp + dv * 4);
                acc += qreg[dv * 4 + 0] * k4.x + qreg[dv * 4 + 1] * k4.y
                     + qreg[dv * 4 + 2] * k4.z + qreg[dv * 4 + 3] * k4.w;
            }
            int j = s - t + 512;
            j = max(0, min(1024, j));
            sc[row][t] = acc + qp[row][j];
        }
        __syncthreads();
    }

    // ---- phase 3: softmax (per wave/row) ----
    float m = -1e30f;
    for (int t = lane; t < SEQ; t += 64) m = fmaxf(m, sc[row][t]);
    #pragma unroll
    for (int off = 32; off; off >>= 1) m = fmaxf(m, __shfl_xor(m, off));
    float sum = 0.f;
    for (int t = lane; t < SEQ; t += 64) {
        float e = __expf(sc[row][t] - m);
        sc[row][t] = e;
        sum += e;
    }
    #pragma unroll
    for (int off = 32; off; off >>= 1) sum += __shfl_xor(sum, off);
    if (lane == 0) rowinv[row] = 1.f / sum;
    __syncthreads();

    // ---- phase 4: ctx ----
    float acc = 0.f;                     // this thread owns d = lane of its row
    for (int t0 = 0; t0 < SEQ; t0 += 64) {
        __syncthreads();                 // previous stg readers done
        for (int e = tid; e < 64 * 64; e += 256) {
            int r = e >> 6, c = e & 63;
            stg[r][c] = kvbuf[(size_t)(b * SEQ + t0 + r) * 1024 + 512 + h * HD + c];
        }
        __syncthreads();
        #pragma unroll 8
        for (int tt = 0; tt < 64; tt++) {
            acc += sc[row][t0 + tt] * stg[tt][lane];
        }
    }
    ctxbuf[(size_t)(b * SEQ + s) * DM + h * HD + lane] = acc * rowinv[row];
}

// ---------------------------------------------------------------------------
extern "C" void kernel_launch(void* const* d_in, const int* in_sizes, int n_in,
                              void* d_out, int out_size, void* d_ws, size_t ws_size,
                              hipStream_t stream) {
    const float* x    = (const float*)d_in[0];
    // d_in[1] attn_mask: unused by the reference computation
    const float* Wq   = (const float*)d_in[2];
    const float* Wkv  = (const float*)d_in[3];
    const float* Wout = (const float*)d_in[4];
    const float* bout = (const float*)d_in[5];
    const float* pemb = (const float*)d_in[6];
    float* out = (float*)d_out;

    const int M = BATCH * SEQ;           // 4096
    float* ws     = (float*)d_ws;
    float* qbuf   = ws;                          // 4096*512  fp32 (8 MB)
    float* kvbuf  = qbuf + (size_t)M * DM;       // 4096*1024 fp32 (16 MB)
    float* ctxbuf = kvbuf + (size_t)M * 2 * DM;  // 4096*512  fp32 (8 MB)

    // q = x @ Wq            [4096,512]
    gemm_f32<<<dim3(DM / 64, M / 64), 256, 0, stream>>>(x, Wq, nullptr, qbuf, M, DM, DM);
    // kv = x @ Wkv          [4096,1024]
    gemm_f32<<<dim3(2 * DM / 64, M / 64), 256, 0, stream>>>(x, Wkv, nullptr, kvbuf, M, 2 * DM, DM);
    // fused attention -> ctx [4096,512]
    attn_kernel<<<dim3(SEQ / QT, BATCH * NH), 256, 0, stream>>>(qbuf, kvbuf, pemb, ctxbuf);
    // out = ctx @ Wout + bout
    gemm_f32<<<dim3(DM / 64, M / 64), 256, 0, stream>>>(ctxbuf, Wout, bout, out, M, DM, DM);
}

// Round 4
// 214.494 us; speedup vs baseline: 9.1287x; 9.1287x over previous
//
#include <hip/hip_runtime.h>
#include <hip/hip_bf16.h>

constexpr int BATCH = 4;
constexpr int SEQ   = 1024;
constexpr int DM    = 512;     // model dim = HEADS*HDIM
constexpr int NH    = 8;
constexpr int HD    = 64;

typedef __attribute__((ext_vector_type(8))) __bf16 bf8;
typedef __attribute__((ext_vector_type(4))) float  f4;

#define MFMA16(a, b, c) __builtin_amdgcn_mfma_f32_16x16x32_bf16(a, b, c, 0, 0, 0)

static __device__ __forceinline__ unsigned short f2b(float f) {
    union { float f; unsigned u; } v; v.f = f;
    unsigned r = v.u + 0x7FFFu + ((v.u >> 16) & 1u);   // RNE; inputs never NaN
    return (unsigned short)(r >> 16);
}
static __device__ __forceinline__ float b2f(unsigned short h) {
    union { unsigned u; float f; } v; v.u = ((unsigned)h) << 16; return v.f;
}

// ---------------------------------------------------------------------------
// float -> bf16 elementwise (n % 4 == 0)
// ---------------------------------------------------------------------------
__global__ __launch_bounds__(256)
void cvt4(const float* __restrict__ in, unsigned short* __restrict__ out, int n) {
    int i = (blockIdx.x * 256 + threadIdx.x) * 4;
    if (i < n) {
        float4 v = *(const float4*)(in + i);
        ushort4 o;
        o.x = f2b(v.x); o.y = f2b(v.y); o.z = f2b(v.z); o.w = f2b(v.w);
        *(ushort4*)(out + i) = o;
    }
}

// ---------------------------------------------------------------------------
// fp32 [R,C] -> bf16 transposed [C,R]   (R,C multiples of 32)
// ---------------------------------------------------------------------------
__global__ __launch_bounds__(256)
void tcvt(const float* __restrict__ in, unsigned short* __restrict__ out, int R, int C) {
    __shared__ float t[32][33];
    int r0 = blockIdx.y * 32, c0 = blockIdx.x * 32;
    int lc = threadIdx.x & 31, lr = threadIdx.x >> 5;   // lr in [0,8)
    #pragma unroll
    for (int p = 0; p < 4; p++) {
        int r = lr + p * 8;
        t[r][lc] = in[(size_t)(r0 + r) * C + c0 + lc];
    }
    __syncthreads();
    #pragma unroll
    for (int p = 0; p < 4; p++) {
        int r = lr + p * 8;
        out[(size_t)(c0 + r) * R + r0 + lc] = f2b(t[lc][r]);
    }
}

// ---------------------------------------------------------------------------
// MFMA GEMM: C[M,N] = A[M,K] @ Bt[N,K]^T   (bf16 in, fp32 acc)
// 128x128 tile, BK=32, 256 threads = 4 waves in 2x2, 4x4 16x16 frags per wave.
// Cb != null -> bf16 out; else fp32 out + bias.
// ---------------------------------------------------------------------------
__global__ __launch_bounds__(256)
void gemm_bt(const unsigned short* __restrict__ A, const unsigned short* __restrict__ Bt,
             int M, int N, int K,
             unsigned short* __restrict__ Cb, float* __restrict__ Cf,
             const float* __restrict__ bias) {
    __shared__ __align__(16) unsigned short As[128][40];
    __shared__ __align__(16) unsigned short Bs[128][40];
    const int tid = threadIdx.x, w = tid >> 6, lane = tid & 63;
    const int l15 = lane & 15, l4 = lane >> 4;
    const int wr = (w >> 1) * 64, wc = (w & 1) * 64;
    const int bm = blockIdx.y * 128, bn = blockIdx.x * 128;

    f4 acc[4][4];
    #pragma unroll
    for (int i = 0; i < 4; i++)
        #pragma unroll
        for (int j = 0; j < 4; j++) acc[i][j] = (f4){0.f, 0.f, 0.f, 0.f};

    const int sr = tid >> 1, sc = (tid & 1) * 16;   // each thread: 16 u16 = 2x bf8
    for (int k0 = 0; k0 < K; k0 += 32) {
        const unsigned short* ga = A  + (size_t)(bm + sr) * K + k0 + sc;
        const unsigned short* gb = Bt + (size_t)(bn + sr) * K + k0 + sc;
        *(bf8*)&As[sr][sc]     = *(const bf8*)ga;
        *(bf8*)&As[sr][sc + 8] = *(const bf8*)(ga + 8);
        *(bf8*)&Bs[sr][sc]     = *(const bf8*)gb;
        *(bf8*)&Bs[sr][sc + 8] = *(const bf8*)(gb + 8);
        __syncthreads();
        bf8 af[4], bf[4];
        #pragma unroll
        for (int i = 0; i < 4; i++) af[i] = *(const bf8*)&As[wr + i * 16 + l15][l4 * 8];
        #pragma unroll
        for (int j = 0; j < 4; j++) bf[j] = *(const bf8*)&Bs[wc + j * 16 + l15][l4 * 8];
        #pragma unroll
        for (int i = 0; i < 4; i++)
            #pragma unroll
            for (int j = 0; j < 4; j++)
                acc[i][j] = MFMA16(af[i], bf[j], acc[i][j]);
        __syncthreads();
    }
    #pragma unroll
    for (int i = 0; i < 4; i++)
        #pragma unroll
        for (int j = 0; j < 4; j++)
            #pragma unroll
            for (int reg = 0; reg < 4; reg++) {
                int row = bm + wr + i * 16 + l4 * 4 + reg;
                int col = bn + wc + j * 16 + l15;
                float v = acc[i][j][reg];
                if (Cb) Cb[(size_t)row * N + col] = f2b(v);
                else    Cf[(size_t)row * N + col] = v + bias[col];
            }
}

// ---------------------------------------------------------------------------
// Fused MFMA flash attention with relative-position term.
// Block = (b,h, 64 q-rows); 4 waves, wave w owns q rows [w*16, w*16+16).
// Sliding 128-col ring Qd[s][j&127] = q_s . pemb[clamp(j)] (bf16), refreshed
// 64 cols per K-tile via MFMA against a staged pemb band.
// ---------------------------------------------------------------------------
__global__ __launch_bounds__(256)
void attn_mfma(const unsigned short* __restrict__ qb, const unsigned short* __restrict__ kvb,
               const unsigned short* __restrict__ pembb, unsigned short* __restrict__ ctxb) {
    __shared__ __align__(16) unsigned short Ks[64][72];   // K tile [t][d]
    __shared__ __align__(16) unsigned short Vt[64][72];   // V tile transposed [d][t]
    __shared__ __align__(16) unsigned short Bd[128][72];  // pemb band [r][d]
    __shared__ __align__(16) unsigned short Ps[64][72];   // P tile [s][t] (wave-private rows)
    __shared__ __align__(16) unsigned short Qd[64][136];  // qdot ring [s][j&127]

    const int tid = threadIdx.x, w = tid >> 6, lane = tid & 63;
    const int l15 = lane & 15, l4 = lane >> 4;
    const int bh = blockIdx.y, b = bh >> 3, h = bh & 7;
    const int s0 = blockIdx.x * 64;

    // Q A-frags from global (rows w*16+l15, k = l4*8+j [+32])
    const unsigned short* qp =
        qb + (size_t)(b * SEQ + s0 + w * 16 + l15) * DM + h * HD + l4 * 8;
    bf8 qa0 = *(const bf8*)qp;
    bf8 qa1 = *(const bf8*)(qp + 32);

    // ---- init: band rows for window 0 (j = s0+449+r, r in [0,128)) ----
    for (int e = tid; e < 128 * 8; e += 256) {
        int r = e >> 3, c = (e & 7) * 8;
        int jc = min(1024, max(0, s0 + 449 + r));
        *(bf8*)&Bd[r][c] = *(const bf8*)(pembb + (size_t)jc * HD + c);
    }
    __syncthreads();
    #pragma unroll
    for (int jt = 0; jt < 8; jt++) {
        bf8 b0 = *(const bf8*)&Bd[jt * 16 + l15][l4 * 8];
        bf8 b1 = *(const bf8*)&Bd[jt * 16 + l15][32 + l4 * 8];
        f4 f = (f4){0.f, 0.f, 0.f, 0.f};
        f = MFMA16(qa0, b0, f);
        f = MFMA16(qa1, b1, f);
        int sl = w * 16 + l4 * 4;
        int j = s0 + 449 + jt * 16 + l15;
        #pragma unroll
        for (int reg = 0; reg < 4; reg++)
            Qd[sl + reg][j & 127] = f2b(f[reg]);
    }
    __syncthreads();

    float m_r[4] = {-1e30f, -1e30f, -1e30f, -1e30f};
    float l_r[4] = {0.f, 0.f, 0.f, 0.f};
    f4 o[4];
    #pragma unroll
    for (int dt = 0; dt < 4; dt++) o[dt] = (f4){0.f, 0.f, 0.f, 0.f};

    for (int i = 0; i < 16; i++) {
        const int t0 = i * 64;
        // ---- staging (full 64-col rows: 8 bf8 chunks per row) ----
        for (int e = tid; e < 64 * 8; e += 256) {
            int r = e >> 3, c = (e & 7) * 8;
            *(bf8*)&Ks[r][c] =
                *(const bf8*)(kvb + (size_t)(b * SEQ + t0 + r) * 1024 + h * HD + c);
        }
        for (int e = tid; e < 4096; e += 256) {
            int t = e >> 6, d = e & 63;
            Vt[d][t] = kvb[(size_t)(b * SEQ + t0 + t) * 1024 + 512 + h * HD + d];
        }
        const int jlo_next = s0 + 449 - 64 * (i + 1);
        if (i < 15) {
            for (int e = tid; e < 64 * 8; e += 256) {
                int r = e >> 3, c = (e & 7) * 8;
                int jc = min(1024, max(0, jlo_next + r));
                *(bf8*)&Bd[r][c] = *(const bf8*)(pembb + (size_t)jc * HD + c);
            }
        }
        __syncthreads();

        // ---- QK^T ----
        f4 s[4];
        #pragma unroll
        for (int jt = 0; jt < 4; jt++) {
            bf8 b0 = *(const bf8*)&Ks[jt * 16 + l15][l4 * 8];
            bf8 b1 = *(const bf8*)&Ks[jt * 16 + l15][32 + l4 * 8];
            f4 acc = (f4){0.f, 0.f, 0.f, 0.f};
            acc = MFMA16(qa0, b0, acc);
            acc = MFMA16(qa1, b1, acc);
            s[jt] = acc;
        }
        // ---- add pos (ring gather) + scale ----
        const int jbase = s0 - t0 + 512;
        float sc[4][4];
        #pragma unroll
        for (int jt = 0; jt < 4; jt++) {
            int tl = jt * 16 + l15;
            #pragma unroll
            for (int reg = 0; reg < 4; reg++) {
                int sl = w * 16 + l4 * 4 + reg;
                int j = jbase + sl - tl;
                sc[jt][reg] = (s[jt][reg] + b2f(Qd[sl][j & 127])) * 0.125f;
            }
        }
        asm volatile("" ::: "memory");
        // ---- online softmax (stats within 16-lane groups) ----
        float mnew[4], alpha[4];
        #pragma unroll
        for (int reg = 0; reg < 4; reg++) {
            float mx = fmaxf(fmaxf(sc[0][reg], sc[1][reg]), fmaxf(sc[2][reg], sc[3][reg]));
            #pragma unroll
            for (int off = 8; off; off >>= 1) mx = fmaxf(mx, __shfl_xor(mx, off));
            mnew[reg] = fmaxf(m_r[reg], mx);
            alpha[reg] = __expf(m_r[reg] - mnew[reg]);
            m_r[reg] = mnew[reg];
        }
        float rs[4] = {0.f, 0.f, 0.f, 0.f};
        #pragma unroll
        for (int jt = 0; jt < 4; jt++)
            #pragma unroll
            for (int reg = 0; reg < 4; reg++) {
                float p = __expf(sc[jt][reg] - mnew[reg]);
                sc[jt][reg] = p;
                rs[reg] += p;
            }
        #pragma unroll
        for (int reg = 0; reg < 4; reg++) {
            float r2 = rs[reg];
            #pragma unroll
            for (int off = 8; off; off >>= 1) r2 += __shfl_xor(r2, off);
            l_r[reg] = l_r[reg] * alpha[reg] + r2;
        }
        #pragma unroll
        for (int dt = 0; dt < 4; dt++)
            #pragma unroll
            for (int reg = 0; reg < 4; reg++) o[dt][reg] *= alpha[reg];
        // ---- P -> LDS (wave-private rows), then PV ----
        #pragma unroll
        for (int jt = 0; jt < 4; jt++)
            #pragma unroll
            for (int reg = 0; reg < 4; reg++)
                Ps[w * 16 + l4 * 4 + reg][jt * 16 + l15] = f2b(sc[jt][reg]);
        asm volatile("" ::: "memory");
        bf8 pa0 = *(const bf8*)&Ps[w * 16 + l15][l4 * 8];
        bf8 pa1 = *(const bf8*)&Ps[w * 16 + l15][32 + l4 * 8];
        #pragma unroll
        for (int dt = 0; dt < 4; dt++) {
            bf8 v0 = *(const bf8*)&Vt[dt * 16 + l15][l4 * 8];
            bf8 v1 = *(const bf8*)&Vt[dt * 16 + l15][32 + l4 * 8];
            o[dt] = MFMA16(pa0, v0, o[dt]);
            o[dt] = MFMA16(pa1, v1, o[dt]);
        }
        // ---- qdot for next window's 64 new cols ----
        if (i < 15) {
            #pragma unroll
            for (int jt = 0; jt < 4; jt++) {
                bf8 b0 = *(const bf8*)&Bd[jt * 16 + l15][l4 * 8];
                bf8 b1 = *(const bf8*)&Bd[jt * 16 + l15][32 + l4 * 8];
                f4 f = (f4){0.f, 0.f, 0.f, 0.f};
                f = MFMA16(qa0, b0, f);
                f = MFMA16(qa1, b1, f);
                int j = jlo_next + jt * 16 + l15;
                #pragma unroll
                for (int reg = 0; reg < 4; reg++)
                    Qd[w * 16 + l4 * 4 + reg][j & 127] = f2b(f[reg]);
            }
        }
        __syncthreads();
    }
    // ---- epilogue ----
    #pragma unroll
    for (int dt = 0; dt < 4; dt++)
        #pragma unroll
        for (int reg = 0; reg < 4; reg++) {
            int srow = s0 + w * 16 + l4 * 4 + reg;
            float v = o[dt][reg] / l_r[reg];
            ctxb[(size_t)(b * SEQ + srow) * DM + h * HD + dt * 16 + l15] = f2b(v);
        }
}

// ---------------------------------------------------------------------------
extern "C" void kernel_launch(void* const* d_in, const int* in_sizes, int n_in,
                              void* d_out, int out_size, void* d_ws, size_t ws_size,
                              hipStream_t stream) {
    const float* x    = (const float*)d_in[0];
    // d_in[1] attn_mask: unused by the reference computation
    const float* Wq   = (const float*)d_in[2];
    const float* Wkv  = (const float*)d_in[3];
    const float* Wout = (const float*)d_in[4];
    const float* bout = (const float*)d_in[5];
    const float* pemb = (const float*)d_in[6];
    float* out = (float*)d_out;

    const int M = BATCH * SEQ;   // 4096
    typedef unsigned short u16;
    u16* p = (u16*)d_ws;
    u16* xb    = p; p += (size_t)M * DM;          // 4096x512
    u16* Wqt   = p; p += (size_t)DM * DM;         // 512x512   (transposed)
    u16* Wkvt  = p; p += (size_t)2 * DM * DM;     // 1024x512  (transposed)
    u16* Woutt = p; p += (size_t)DM * DM;         // 512x512   (transposed)
    u16* pembb = p; p += (size_t)1025 * HD;       // 1025x64
    u16* qbuf  = p; p += (size_t)M * DM;          // 4096x512
    u16* kvbuf = p; p += (size_t)M * 2 * DM;      // 4096x1024
    u16* ctxb  = p; p += (size_t)M * DM;          // 4096x512

    cvt4<<<(M * DM) / 4 / 256, 256, 0, stream>>>(x, xb, M * DM);
    tcvt<<<dim3(16, 16), 256, 0, stream>>>(Wq,   Wqt,   DM, DM);
    tcvt<<<dim3(32, 16), 256, 0, stream>>>(Wkv,  Wkvt,  DM, 2 * DM);
    tcvt<<<dim3(16, 16), 256, 0, stream>>>(Wout, Woutt, DM, DM);
    cvt4<<<(1025 * HD / 4 + 255) / 256, 256, 0, stream>>>(pemb, pembb, 1025 * HD);

    gemm_bt<<<dim3(DM / 128, M / 128), 256, 0, stream>>>(xb, Wqt, M, DM, DM,
                                                         qbuf, nullptr, nullptr);
    gemm_bt<<<dim3(2 * DM / 128, M / 128), 256, 0, stream>>>(xb, Wkvt, M, 2 * DM, DM,
                                                             kvbuf, nullptr, nullptr);
    attn_mfma<<<dim3(SEQ / 64, BATCH * NH), 256, 0, stream>>>(qbuf, kvbuf, pembb, ctxb);
    gemm_bt<<<dim3(DM / 128, M / 128), 256, 0, stream>>>(ctxb, Woutt, M, DM, DM,
                                                         nullptr, out, bout);
}

// Round 5
// 194.406 us; speedup vs baseline: 10.0720x; 1.1033x over previous
//
#include <hip/hip_runtime.h>
#include <hip/hip_bf16.h>

constexpr int BATCH = 4;
constexpr int SEQ   = 1024;
constexpr int DM    = 512;     // model dim = HEADS*HDIM
constexpr int NH    = 8;
constexpr int HD    = 64;
constexpr int NQKV  = 1536;    // q(512) + k(512) + v(512) fused projection width

typedef __attribute__((ext_vector_type(8))) __bf16 bf8;
typedef __attribute__((ext_vector_type(4))) float  f4;

#define MFMA16(a, b, c) __builtin_amdgcn_mfma_f32_16x16x32_bf16(a, b, c, 0, 0, 0)

static __device__ __forceinline__ unsigned short f2b(float f) {
    union { float f; unsigned u; } v; v.f = f;
    unsigned r = v.u + 0x7FFFu + ((v.u >> 16) & 1u);   // RNE; inputs never NaN
    return (unsigned short)(r >> 16);
}
static __device__ __forceinline__ float b2f(unsigned short h) {
    union { unsigned u; float f; } v; v.u = ((unsigned)h) << 16; return v.f;
}

// ---------------------------------------------------------------------------
// float -> bf16 elementwise (n % 4 == 0)
// ---------------------------------------------------------------------------
__global__ __launch_bounds__(256)
void cvt4(const float* __restrict__ in, unsigned short* __restrict__ out, int n) {
    int i = (blockIdx.x * 256 + threadIdx.x) * 4;
    if (i < n) {
        float4 v = *(const float4*)(in + i);
        ushort4 o;
        o.x = f2b(v.x); o.y = f2b(v.y); o.z = f2b(v.z); o.w = f2b(v.w);
        *(ushort4*)(out + i) = o;
    }
}

// ---------------------------------------------------------------------------
// fp32 [R,C] -> bf16 transposed [C,R]   (R,C multiples of 32)
// ---------------------------------------------------------------------------
__global__ __launch_bounds__(256)
void tcvt(const float* __restrict__ in, unsigned short* __restrict__ out, int R, int C) {
    __shared__ float t[32][33];
    int r0 = blockIdx.y * 32, c0 = blockIdx.x * 32;
    int lc = threadIdx.x & 31, lr = threadIdx.x >> 5;   // lr in [0,8)
    #pragma unroll
    for (int p = 0; p < 4; p++) {
        int r = lr + p * 8;
        t[r][lc] = in[(size_t)(r0 + r) * C + c0 + lc];
    }
    __syncthreads();
    #pragma unroll
    for (int p = 0; p < 4; p++) {
        int r = lr + p * 8;
        out[(size_t)(c0 + r) * R + r0 + lc] = f2b(t[lc][r]);
    }
}

// ---------------------------------------------------------------------------
// V transpose: qkv[4096][1536] cols [1024,1536) -> vtb[(b*8+h)*64+d][1024] (t)
// 64x64 tile per block via LDS; all global accesses coalesced.
// ---------------------------------------------------------------------------
__global__ __launch_bounds__(256)
void vtrans(const unsigned short* __restrict__ qkv, unsigned short* __restrict__ vtb) {
    __shared__ unsigned short T[64][66];   // 66 pad: read bank = t + d/2 (2-way, free)
    const int tid = threadIdx.x;
    const int t0 = blockIdx.x * 64;
    const int bh = blockIdx.y;             // b*8+h
    const unsigned short* src =
        qkv + (size_t)((bh >> 3) * SEQ + t0) * NQKV + 1024 + (bh & 7) * 64;
    for (int e = tid; e < 4096; e += 256) {
        int t = e >> 6, d = e & 63;
        T[t][d] = src[(size_t)t * NQKV + d];
    }
    __syncthreads();
    unsigned short* dst = vtb + (size_t)bh * 64 * 1024 + t0;
    for (int e = tid; e < 4096; e += 256) {
        int d = e >> 6, t = e & 63;
        dst[(size_t)d * 1024 + t] = T[t][d];
    }
}

// ---------------------------------------------------------------------------
// MFMA GEMM: C[M,N] = A[M,K] @ Bt[N,K]^T   (bf16 in, fp32 acc)
// 128x128 tile, BK=32, 256 threads = 4 waves in 2x2, 4x4 16x16 frags per wave.
// Cb != null -> bf16 out; else fp32 out + bias.
// ---------------------------------------------------------------------------
__global__ __launch_bounds__(256)
void gemm_bt(const unsigned short* __restrict__ A, const unsigned short* __restrict__ Bt,
             int M, int N, int K,
             unsigned short* __restrict__ Cb, float* __restrict__ Cf,
             const float* __restrict__ bias) {
    __shared__ __align__(16) unsigned short As[128][40];
    __shared__ __align__(16) unsigned short Bs[128][40];
    const int tid = threadIdx.x, w = tid >> 6, lane = tid & 63;
    const int l15 = lane & 15, l4 = lane >> 4;
    const int wr = (w >> 1) * 64, wc = (w & 1) * 64;
    const int bm = blockIdx.y * 128, bn = blockIdx.x * 128;

    f4 acc[4][4];
    #pragma unroll
    for (int i = 0; i < 4; i++)
        #pragma unroll
        for (int j = 0; j < 4; j++) acc[i][j] = (f4){0.f, 0.f, 0.f, 0.f};

    const int sr = tid >> 1, sc = (tid & 1) * 16;   // each thread: 16 u16 = 2x bf8
    for (int k0 = 0; k0 < K; k0 += 32) {
        const unsigned short* ga = A  + (size_t)(bm + sr) * K + k0 + sc;
        const unsigned short* gb = Bt + (size_t)(bn + sr) * K + k0 + sc;
        *(bf8*)&As[sr][sc]     = *(const bf8*)ga;
        *(bf8*)&As[sr][sc + 8] = *(const bf8*)(ga + 8);
        *(bf8*)&Bs[sr][sc]     = *(const bf8*)gb;
        *(bf8*)&Bs[sr][sc + 8] = *(const bf8*)(gb + 8);
        __syncthreads();
        bf8 af[4], bf[4];
        #pragma unroll
        for (int i = 0; i < 4; i++) af[i] = *(const bf8*)&As[wr + i * 16 + l15][l4 * 8];
        #pragma unroll
        for (int j = 0; j < 4; j++) bf[j] = *(const bf8*)&Bs[wc + j * 16 + l15][l4 * 8];
        #pragma unroll
        for (int i = 0; i < 4; i++)
            #pragma unroll
            for (int j = 0; j < 4; j++)
                acc[i][j] = MFMA16(af[i], bf[j], acc[i][j]);
        __syncthreads();
    }
    #pragma unroll
    for (int i = 0; i < 4; i++)
        #pragma unroll
        for (int j = 0; j < 4; j++)
            #pragma unroll
            for (int reg = 0; reg < 4; reg++) {
                int row = bm + wr + i * 16 + l4 * 4 + reg;
                int col = bn + wc + j * 16 + l15;
                float v = acc[i][j][reg];
                if (Cb) Cb[(size_t)row * N + col] = f2b(v);
                else    Cf[(size_t)row * N + col] = v + bias[col];
            }
}

// ---------------------------------------------------------------------------
// Fused MFMA flash attention with relative-position term.
// Block = (b,h, 64 q-rows); 4 waves, wave w owns q rows [w*16, w*16+16).
// q pre-scaled by 0.125 (exact exponent shift). Sliding 128-col ring
// Qd[s][j&127] = q_s . pemb[clamp(j)] refreshed 64 cols/K-tile via MFMA.
// V arrives pre-transposed (vtb) -> vectorized coalesced staging.
// LDS 53.8 KB -> 3 blocks/CU.
// ---------------------------------------------------------------------------
__global__ __launch_bounds__(256, 3)
void attn_mfma(const unsigned short* __restrict__ qkv, const unsigned short* __restrict__ vtb,
               const unsigned short* __restrict__ pembb, unsigned short* __restrict__ ctxb) {
    __shared__ __align__(16) unsigned short Ks[64][72];   // K tile [t][d]
    __shared__ __align__(16) unsigned short Vt[64][72];   // V tile [d][t] (pre-transposed)
    __shared__ __align__(16) unsigned short Bd[64][72];   // pemb band [r][d]
    __shared__ __align__(16) unsigned short Ps[64][72];   // P tile [s][t] (wave-private rows)
    __shared__ __align__(16) unsigned short Qd[64][136];  // qdot ring [s][j&127]

    const int tid = threadIdx.x, w = tid >> 6, lane = tid & 63;
    const int l15 = lane & 15, l4 = lane >> 4;
    const int bh = blockIdx.y, b = bh >> 3, h = bh & 7;
    const int s0 = blockIdx.x * 64;

    // Q A-frags (rows w*16+l15, k = l4*8 [+32]), pre-scaled by 2^-3 (exact)
    bf8 qa0, qa1;
    {
        const unsigned short* qp =
            qkv + (size_t)(b * SEQ + s0 + w * 16 + l15) * NQKV + h * HD + l4 * 8;
        union { bf8 v; unsigned short u[8]; } a0, a1;
        a0.v = *(const bf8*)qp;
        a1.v = *(const bf8*)(qp + 32);
        #pragma unroll
        for (int i = 0; i < 8; i++) {
            a0.u[i] = f2b(b2f(a0.u[i]) * 0.125f);
            a1.u[i] = f2b(b2f(a1.u[i]) * 0.125f);
        }
        qa0 = a0.v; qa1 = a1.v;
    }

    // ---- init ring (127 cols j in [s0+449, s0+576]) in two 64-row passes ----
    #pragma unroll
    for (int pass = 0; pass < 2; pass++) {
        const int jlo = s0 + 449 + pass * 64;
        for (int e = tid; e < 64 * 8; e += 256) {
            int r = e >> 3, c = (e & 7) * 8;
            int jc = min(1024, max(0, jlo + r));
            *(bf8*)&Bd[r][c] = *(const bf8*)(pembb + (size_t)jc * HD + c);
        }
        __syncthreads();
        #pragma unroll
        for (int jt = 0; jt < 4; jt++) {
            bf8 b0 = *(const bf8*)&Bd[jt * 16 + l15][l4 * 8];
            bf8 b1 = *(const bf8*)&Bd[jt * 16 + l15][32 + l4 * 8];
            f4 f = (f4){0.f, 0.f, 0.f, 0.f};
            f = MFMA16(qa0, b0, f);
            f = MFMA16(qa1, b1, f);
            int sl = w * 16 + l4 * 4;
            int j = jlo + jt * 16 + l15;
            #pragma unroll
            for (int reg = 0; reg < 4; reg++)
                Qd[sl + reg][j & 127] = f2b(f[reg]);
        }
        __syncthreads();
    }

    float m_r[4] = {-1e30f, -1e30f, -1e30f, -1e30f};
    float l_r[4] = {0.f, 0.f, 0.f, 0.f};
    f4 o[4];
    #pragma unroll
    for (int dt = 0; dt < 4; dt++) o[dt] = (f4){0.f, 0.f, 0.f, 0.f};

    const unsigned short* kbase = qkv + (size_t)(b * SEQ) * NQKV + 512 + h * HD;
    const unsigned short* vbase = vtb + (size_t)bh * HD * SEQ;

    for (int i = 0; i < 16; i++) {
        const int t0 = i * 64;
        // ---- staging (all vectorized, coalesced) ----
        for (int e = tid; e < 64 * 8; e += 256) {
            int r = e >> 3, c = (e & 7) * 8;
            *(bf8*)&Ks[r][c] = *(const bf8*)(kbase + (size_t)(t0 + r) * NQKV + c);
        }
        for (int e = tid; e < 64 * 8; e += 256) {
            int d = e >> 3, c = (e & 7) * 8;
            *(bf8*)&Vt[d][c] = *(const bf8*)(vbase + (size_t)d * SEQ + t0 + c);
        }
        const int jlo_next = s0 + 449 - 64 * (i + 1);
        if (i < 15) {
            for (int e = tid; e < 64 * 8; e += 256) {
                int r = e >> 3, c = (e & 7) * 8;
                int jc = min(1024, max(0, jlo_next + r));
                *(bf8*)&Bd[r][c] = *(const bf8*)(pembb + (size_t)jc * HD + c);
            }
        }
        __syncthreads();

        // ---- QK^T (q pre-scaled) ----
        f4 s[4];
        #pragma unroll
        for (int jt = 0; jt < 4; jt++) {
            bf8 b0 = *(const bf8*)&Ks[jt * 16 + l15][l4 * 8];
            bf8 b1 = *(const bf8*)&Ks[jt * 16 + l15][32 + l4 * 8];
            f4 acc = (f4){0.f, 0.f, 0.f, 0.f};
            acc = MFMA16(qa0, b0, acc);
            acc = MFMA16(qa1, b1, acc);
            s[jt] = acc;
        }
        // ---- add pos (ring gather; Qd already scaled via q) ----
        const int jbase = s0 - t0 + 512;
        float sc[4][4];
        #pragma unroll
        for (int jt = 0; jt < 4; jt++) {
            int tl = jt * 16 + l15;
            #pragma unroll
            for (int reg = 0; reg < 4; reg++) {
                int sl = w * 16 + l4 * 4 + reg;
                int j = jbase + sl - tl;
                sc[jt][reg] = s[jt][reg] + b2f(Qd[sl][j & 127]);
            }
        }
        asm volatile("" ::: "memory");
        // ---- online softmax (stats within 16-lane groups) ----
        float mnew[4], alpha[4];
        #pragma unroll
        for (int reg = 0; reg < 4; reg++) {
            float mx = fmaxf(fmaxf(sc[0][reg], sc[1][reg]), fmaxf(sc[2][reg], sc[3][reg]));
            #pragma unroll
            for (int off = 8; off; off >>= 1) mx = fmaxf(mx, __shfl_xor(mx, off));
            mnew[reg] = fmaxf(m_r[reg], mx);
            alpha[reg] = __expf(m_r[reg] - mnew[reg]);
            m_r[reg] = mnew[reg];
        }
        float rs[4] = {0.f, 0.f, 0.f, 0.f};
        #pragma unroll
        for (int jt = 0; jt < 4; jt++)
            #pragma unroll
            for (int reg = 0; reg < 4; reg++) {
                float p = __expf(sc[jt][reg] - mnew[reg]);
                sc[jt][reg] = p;
                rs[reg] += p;
            }
        #pragma unroll
        for (int reg = 0; reg < 4; reg++) {
            float r2 = rs[reg];
            #pragma unroll
            for (int off = 8; off; off >>= 1) r2 += __shfl_xor(r2, off);
            l_r[reg] = l_r[reg] * alpha[reg] + r2;
        }
        #pragma unroll
        for (int dt = 0; dt < 4; dt++)
            #pragma unroll
            for (int reg = 0; reg < 4; reg++) o[dt][reg] *= alpha[reg];
        // ---- P -> LDS (wave-private rows), then PV ----
        #pragma unroll
        for (int jt = 0; jt < 4; jt++)
            #pragma unroll
            for (int reg = 0; reg < 4; reg++)
                Ps[w * 16 + l4 * 4 + reg][jt * 16 + l15] = f2b(sc[jt][reg]);
        asm volatile("" ::: "memory");
        bf8 pa0 = *(const bf8*)&Ps[w * 16 + l15][l4 * 8];
        bf8 pa1 = *(const bf8*)&Ps[w * 16 + l15][32 + l4 * 8];
        #pragma unroll
        for (int dt = 0; dt < 4; dt++) {
            bf8 v0 = *(const bf8*)&Vt[dt * 16 + l15][l4 * 8];
            bf8 v1 = *(const bf8*)&Vt[dt * 16 + l15][32 + l4 * 8];
            o[dt] = MFMA16(pa0, v0, o[dt]);
            o[dt] = MFMA16(pa1, v1, o[dt]);
        }
        // ---- qdot for next window's 64 new cols ----
        if (i < 15) {
            #pragma unroll
            for (int jt = 0; jt < 4; jt++) {
                bf8 b0 = *(const bf8*)&Bd[jt * 16 + l15][l4 * 8];
                bf8 b1 = *(const bf8*)&Bd[jt * 16 + l15][32 + l4 * 8];
                f4 f = (f4){0.f, 0.f, 0.f, 0.f};
                f = MFMA16(qa0, b0, f);
                f = MFMA16(qa1, b1, f);
                int j = jlo_next + jt * 16 + l15;
                #pragma unroll
                for (int reg = 0; reg < 4; reg++)
                    Qd[w * 16 + l4 * 4 + reg][j & 127] = f2b(f[reg]);
            }
        }
        __syncthreads();
    }
    // ---- epilogue ----
    #pragma unroll
    for (int dt = 0; dt < 4; dt++)
        #pragma unroll
        for (int reg = 0; reg < 4; reg++) {
            int srow = s0 + w * 16 + l4 * 4 + reg;
            float v = o[dt][reg] / l_r[reg];
            ctxb[(size_t)(b * SEQ + srow) * DM + h * HD + dt * 16 + l15] = f2b(v);
        }
}

// ---------------------------------------------------------------------------
extern "C" void kernel_launch(void* const* d_in, const int* in_sizes, int n_in,
                              void* d_out, int out_size, void* d_ws, size_t ws_size,
                              hipStream_t stream) {
    const float* x    = (const float*)d_in[0];
    // d_in[1] attn_mask: unused by the reference computation
    const float* Wq   = (const float*)d_in[2];
    const float* Wkv  = (const float*)d_in[3];
    const float* Wout = (const float*)d_in[4];
    const float* bout = (const float*)d_in[5];
    const float* pemb = (const float*)d_in[6];
    float* out = (float*)d_out;

    const int M = BATCH * SEQ;   // 4096
    typedef unsigned short u16;
    u16* p = (u16*)d_ws;
    u16* xb    = p; p += (size_t)M * DM;          // 4096x512 (dead after QKV gemm)
    u16* vtb   = xb;                              // aliases xb: 32x64x1024
    u16* qkvw  = p; p += (size_t)NQKV * DM;       // 1536x512 (Wq^T ++ Wkv^T)
    u16* Woutt = p; p += (size_t)DM * DM;         // 512x512
    u16* pembb = p; p += (size_t)1025 * HD;       // 1025x64
    u16* qkv   = p; p += (size_t)M * NQKV;        // 4096x1536
    u16* ctxb  = p; p += (size_t)M * DM;          // 4096x512

    cvt4<<<(M * DM) / 4 / 256, 256, 0, stream>>>(x, xb, M * DM);
    tcvt<<<dim3(16, 16), 256, 0, stream>>>(Wq,   qkvw,            DM, DM);
    tcvt<<<dim3(32, 16), 256, 0, stream>>>(Wkv,  qkvw + DM * DM,  DM, 2 * DM);
    tcvt<<<dim3(16, 16), 256, 0, stream>>>(Wout, Woutt,           DM, DM);
    cvt4<<<(1025 * HD / 4 + 255) / 256, 256, 0, stream>>>(pemb, pembb, 1025 * HD);

    // qkv = x @ [Wq | Wkv]    [4096,1536]
    gemm_bt<<<dim3(NQKV / 128, M / 128), 256, 0, stream>>>(xb, qkvw, M, NQKV, DM,
                                                           qkv, nullptr, nullptr);
    // V -> [b,h,d,t] (vtb aliases xb, which is dead now)
    vtrans<<<dim3(SEQ / 64, BATCH * NH), 256, 0, stream>>>(qkv, vtb);
    // fused attention -> ctx [4096,512]
    attn_mfma<<<dim3(SEQ / 64, BATCH * NH), 256, 0, stream>>>(qkv, vtb, pembb, ctxb);
    // out = ctx @ Wout + bout
    gemm_bt<<<dim3(DM / 128, M / 128), 256, 0, stream>>>(ctxb, Woutt, M, DM, DM,
                                                         nullptr, out, bout);
}

// Round 6
// 192.431 us; speedup vs baseline: 10.1754x; 1.0103x over previous
//
#include <hip/hip_runtime.h>
#include <hip/hip_bf16.h>

constexpr int BATCH = 4;
constexpr int SEQ   = 1024;
constexpr int DM    = 512;     // model dim = HEADS*HDIM
constexpr int NH    = 8;
constexpr int HD    = 64;
constexpr int NQKV  = 1536;    // q(512) + k(512) + v(512) fused projection width

typedef __attribute__((ext_vector_type(8))) __bf16 bf8;
typedef __attribute__((ext_vector_type(4))) float  f4;

#define MFMA16(a, b, c) __builtin_amdgcn_mfma_f32_16x16x32_bf16(a, b, c, 0, 0, 0)

static __device__ __forceinline__ unsigned short f2b(float f) {
    union { float f; unsigned u; } v; v.f = f;
    unsigned r = v.u + 0x7FFFu + ((v.u >> 16) & 1u);   // RNE; inputs never NaN
    return (unsigned short)(r >> 16);
}
static __device__ __forceinline__ float b2f(unsigned short h) {
    union { unsigned u; float f; } v; v.u = ((unsigned)h) << 16; return v.f;
}
// async global->LDS, 16 B per lane (dst = wave-uniform base + lane*16)
static __device__ __forceinline__ void gl_lds16(const void* g, void* l) {
    __builtin_amdgcn_global_load_lds(
        (const __attribute__((address_space(1))) void*)g,
        (__attribute__((address_space(3))) void*)l, 16, 0, 0);
}

// ---------------------------------------------------------------------------
// float -> bf16 elementwise (n % 4 == 0)
// ---------------------------------------------------------------------------
__global__ __launch_bounds__(256)
void cvt4(const float* __restrict__ in, unsigned short* __restrict__ out, int n) {
    int i = (blockIdx.x * 256 + threadIdx.x) * 4;
    if (i < n) {
        float4 v = *(const float4*)(in + i);
        ushort4 o;
        o.x = f2b(v.x); o.y = f2b(v.y); o.z = f2b(v.z); o.w = f2b(v.w);
        *(ushort4*)(out + i) = o;
    }
}

// ---------------------------------------------------------------------------
// fp32 [R,C] -> bf16 transposed [C,R]   (R,C multiples of 32)
// ---------------------------------------------------------------------------
__global__ __launch_bounds__(256)
void tcvt(const float* __restrict__ in, unsigned short* __restrict__ out, int R, int C) {
    __shared__ float t[32][33];
    int r0 = blockIdx.y * 32, c0 = blockIdx.x * 32;
    int lc = threadIdx.x & 31, lr = threadIdx.x >> 5;   // lr in [0,8)
    #pragma unroll
    for (int p = 0; p < 4; p++) {
        int r = lr + p * 8;
        t[r][lc] = in[(size_t)(r0 + r) * C + c0 + lc];
    }
    __syncthreads();
    #pragma unroll
    for (int p = 0; p < 4; p++) {
        int r = lr + p * 8;
        out[(size_t)(c0 + r) * R + r0 + lc] = f2b(t[lc][r]);
    }
}

// ---------------------------------------------------------------------------
// V transpose: qkv[4096][1536] cols [1024,1536) -> vtb[(b*8+h)*64+d][1024] (t)
// ---------------------------------------------------------------------------
__global__ __launch_bounds__(256)
void vtrans(const unsigned short* __restrict__ qkv, unsigned short* __restrict__ vtb) {
    __shared__ unsigned short T[64][66];
    const int tid = threadIdx.x;
    const int t0 = blockIdx.x * 64;
    const int bh = blockIdx.y;             // b*8+h
    const unsigned short* src =
        qkv + (size_t)((bh >> 3) * SEQ + t0) * NQKV + 1024 + (bh & 7) * 64;
    for (int e = tid; e < 4096; e += 256) {
        int t = e >> 6, d = e & 63;
        T[t][d] = src[(size_t)t * NQKV + d];
    }
    __syncthreads();
    unsigned short* dst = vtb + (size_t)bh * 64 * 1024 + t0;
    for (int e = tid; e < 4096; e += 256) {
        int d = e >> 6, t = e & 63;
        dst[(size_t)d * 1024 + t] = T[t][d];
    }
}

// ---------------------------------------------------------------------------
// MFMA GEMM (m97 structure): C[M,N] = A[M,K] @ Bt[N,K]^T   (bf16 in, fp32 acc)
// 128x128 tile, BK=32, 256 threads = 4 waves (2x2), 4x4 16x16x32 frags/wave.
// Staging via global_load_lds width=16 into UNPADDED [128][32] tiles.
// ---------------------------------------------------------------------------
__global__ __launch_bounds__(256)
void gemm_bt(const unsigned short* __restrict__ A, const unsigned short* __restrict__ Bt,
             int M, int N, int K,
             __bf16* __restrict__ Cb, float* __restrict__ Cf,
             const float* __restrict__ bias) {
    __shared__ __align__(16) unsigned short As[128][32];
    __shared__ __align__(16) unsigned short Bs[128][32];
    const int tid = threadIdx.x, w = tid >> 6, lane = tid & 63;
    const int l15 = lane & 15, l4 = lane >> 4;
    const int wr = (w >> 1) * 64, wc = (w & 1) * 64;
    const int bm = blockIdx.y * 128, bn = blockIdx.x * 128;

    f4 acc[4][4];
    #pragma unroll
    for (int i = 0; i < 4; i++)
        #pragma unroll
        for (int j = 0; j < 4; j++) acc[i][j] = (f4){0.f, 0.f, 0.f, 0.f};

    // staging map: issue n of wave w covers LDS rows [(w*2+n)*16, +16)
    const int r0 = (w * 2) * 16 + (lane >> 2);
    const int r1 = (w * 2 + 1) * 16 + (lane >> 2);
    const int cs = (lane & 3) * 8;

    for (int k0 = 0; k0 < K; k0 += 32) {
        gl_lds16(A  + (size_t)(bm + r0) * K + k0 + cs, &As[(w * 2) * 16][0]);
        gl_lds16(A  + (size_t)(bm + r1) * K + k0 + cs, &As[(w * 2 + 1) * 16][0]);
        gl_lds16(Bt + (size_t)(bn + r0) * K + k0 + cs, &Bs[(w * 2) * 16][0]);
        gl_lds16(Bt + (size_t)(bn + r1) * K + k0 + cs, &Bs[(w * 2 + 1) * 16][0]);
        __syncthreads();
        bf8 af[4], bf[4];
        #pragma unroll
        for (int i = 0; i < 4; i++) af[i] = *(const bf8*)&As[wr + i * 16 + l15][l4 * 8];
        #pragma unroll
        for (int j = 0; j < 4; j++) bf[j] = *(const bf8*)&Bs[wc + j * 16 + l15][l4 * 8];
        #pragma unroll
        for (int i = 0; i < 4; i++)
            #pragma unroll
            for (int j = 0; j < 4; j++)
                acc[i][j] = MFMA16(af[i], bf[j], acc[i][j]);
        __syncthreads();
    }
    #pragma unroll
    for (int i = 0; i < 4; i++)
        #pragma unroll
        for (int j = 0; j < 4; j++)
            #pragma unroll
            for (int reg = 0; reg < 4; reg++) {
                int row = bm + wr + i * 16 + l4 * 4 + reg;
                int col = bn + wc + j * 16 + l15;
                float v = acc[i][j][reg];
                if (Cb) Cb[(size_t)row * N + col] = (__bf16)v;
                else    Cf[(size_t)row * N + col] = v + bias[col];
            }
}

// ---------------------------------------------------------------------------
// Fused MFMA flash attention with relative-position term.
// Block = (b,h, 64 q-rows); 4 waves, wave w owns q rows [w*16, w*16+16).
// q pre-scaled by 0.125. Sliding 128-col ring Qd[s][j&127] = q_s.pemb[clamp(j)]
// refreshed 64 cols/K-tile via MFMA. Native __bf16 LDS + hardware cvts.
// ---------------------------------------------------------------------------
__global__ __launch_bounds__(256)
void attn_mfma(const unsigned short* __restrict__ qkv, const unsigned short* __restrict__ vtb,
               const unsigned short* __restrict__ pembb, __bf16* __restrict__ ctxb) {
    __shared__ __align__(16) __bf16 Ks[64][72];   // K tile [t][d]
    __shared__ __align__(16) __bf16 Vt[64][72];   // V tile [d][t] (pre-transposed)
    __shared__ __align__(16) __bf16 Bd[64][72];   // pemb band [r][d]
    __shared__ __align__(16) __bf16 Ps[64][72];   // P tile [s][t] (wave-private rows)
    __shared__ __align__(16) __bf16 Qd[64][136];  // qdot ring [s][j&127]

    const int tid = threadIdx.x, w = tid >> 6, lane = tid & 63;
    const int l15 = lane & 15, l4 = lane >> 4;
    const int bh = blockIdx.y, b = bh >> 3, h = bh & 7;
    const int s0 = blockIdx.x * 64;

    // Q A-frags (rows w*16+l15, k = l4*8 [+32]), pre-scaled by 2^-3 (exact)
    bf8 qa0, qa1;
    {
        const unsigned short* qp =
            qkv + (size_t)(b * SEQ + s0 + w * 16 + l15) * NQKV + h * HD + l4 * 8;
        union { bf8 v; unsigned short u[8]; } a0, a1;
        a0.v = *(const bf8*)qp;
        a1.v = *(const bf8*)(qp + 32);
        #pragma unroll
        for (int i = 0; i < 8; i++) {
            a0.u[i] = f2b(b2f(a0.u[i]) * 0.125f);
            a1.u[i] = f2b(b2f(a1.u[i]) * 0.125f);
        }
        qa0 = a0.v; qa1 = a1.v;
    }

    // ---- init ring (127 cols j in [s0+449, s0+576]) in two 64-row passes ----
    #pragma unroll
    for (int pass = 0; pass < 2; pass++) {
        const int jlo = s0 + 449 + pass * 64;
        for (int e = tid; e < 64 * 8; e += 256) {
            int r = e >> 3, c = (e & 7) * 8;
            int jc = min(1024, max(0, jlo + r));
            *(bf8*)&Bd[r][c] = *(const bf8*)(pembb + (size_t)jc * HD + c);
        }
        __syncthreads();
        #pragma unroll
        for (int jt = 0; jt < 4; jt++) {
            bf8 b0 = *(const bf8*)&Bd[jt * 16 + l15][l4 * 8];
            bf8 b1 = *(const bf8*)&Bd[jt * 16 + l15][32 + l4 * 8];
            f4 f = (f4){0.f, 0.f, 0.f, 0.f};
            f = MFMA16(qa0, b0, f);
            f = MFMA16(qa1, b1, f);
            int sl = w * 16 + l4 * 4;
            int j = jlo + jt * 16 + l15;
            #pragma unroll
            for (int reg = 0; reg < 4; reg++)
                Qd[sl + reg][j & 127] = (__bf16)f[reg];
        }
        __syncthreads();
    }

    float m_r[4] = {-1e30f, -1e30f, -1e30f, -1e30f};
    float l_r[4] = {0.f, 0.f, 0.f, 0.f};
    f4 o[4];
    #pragma unroll
    for (int dt = 0; dt < 4; dt++) o[dt] = (f4){0.f, 0.f, 0.f, 0.f};

    const unsigned short* kbase = qkv + (size_t)(b * SEQ) * NQKV + 512 + h * HD;
    const unsigned short* vbase = vtb + (size_t)bh * HD * SEQ;

    for (int i = 0; i < 16; i++) {
        const int t0 = i * 64;
        // ---- staging (vectorized, coalesced) ----
        for (int e = tid; e < 64 * 8; e += 256) {
            int r = e >> 3, c = (e & 7) * 8;
            *(bf8*)&Ks[r][c] = *(const bf8*)(kbase + (size_t)(t0 + r) * NQKV + c);
        }
        for (int e = tid; e < 64 * 8; e += 256) {
            int d = e >> 3, c = (e & 7) * 8;
            *(bf8*)&Vt[d][c] = *(const bf8*)(vbase + (size_t)d * SEQ + t0 + c);
        }
        const int jlo_next = s0 + 449 - 64 * (i + 1);
        if (i < 15) {
            for (int e = tid; e < 64 * 8; e += 256) {
                int r = e >> 3, c = (e & 7) * 8;
                int jc = min(1024, max(0, jlo_next + r));
                *(bf8*)&Bd[r][c] = *(const bf8*)(pembb + (size_t)jc * HD + c);
            }
        }
        __syncthreads();

        // ---- QK^T (q pre-scaled) ----
        f4 s[4];
        #pragma unroll
        for (int jt = 0; jt < 4; jt++) {
            bf8 b0 = *(const bf8*)&Ks[jt * 16 + l15][l4 * 8];
            bf8 b1 = *(const bf8*)&Ks[jt * 16 + l15][32 + l4 * 8];
            f4 acc = (f4){0.f, 0.f, 0.f, 0.f};
            acc = MFMA16(qa0, b0, acc);
            acc = MFMA16(qa1, b1, acc);
            s[jt] = acc;
        }
        // ---- add pos (ring gather; Qd already scaled via q) ----
        const int jbase = s0 - t0 + 512;
        float sc[4][4];
        #pragma unroll
        for (int jt = 0; jt < 4; jt++) {
            int tl = jt * 16 + l15;
            #pragma unroll
            for (int reg = 0; reg < 4; reg++) {
                int sl = w * 16 + l4 * 4 + reg;
                int j = jbase + sl - tl;
                sc[jt][reg] = s[jt][reg] + (float)Qd[sl][j & 127];
            }
        }
        asm volatile("" ::: "memory");
        // ---- online softmax (stats within 16-lane groups) ----
        float mnew[4], alpha[4];
        #pragma unroll
        for (int reg = 0; reg < 4; reg++) {
            float mx = fmaxf(fmaxf(sc[0][reg], sc[1][reg]), fmaxf(sc[2][reg], sc[3][reg]));
            #pragma unroll
            for (int off = 8; off; off >>= 1) mx = fmaxf(mx, __shfl_xor(mx, off));
            mnew[reg] = fmaxf(m_r[reg], mx);
            alpha[reg] = __expf(m_r[reg] - mnew[reg]);
            m_r[reg] = mnew[reg];
        }
        float rs[4] = {0.f, 0.f, 0.f, 0.f};
        #pragma unroll
        for (int jt = 0; jt < 4; jt++)
            #pragma unroll
            for (int reg = 0; reg < 4; reg++) {
                float p = __expf(sc[jt][reg] - mnew[reg]);
                sc[jt][reg] = p;
                rs[reg] += p;
            }
        #pragma unroll
        for (int reg = 0; reg < 4; reg++) {
            float r2 = rs[reg];
            #pragma unroll
            for (int off = 8; off; off >>= 1) r2 += __shfl_xor(r2, off);
            l_r[reg] = l_r[reg] * alpha[reg] + r2;
        }
        #pragma unroll
        for (int dt = 0; dt < 4; dt++)
            #pragma unroll
            for (int reg = 0; reg < 4; reg++) o[dt][reg] *= alpha[reg];
        // ---- P -> LDS (wave-private rows), then PV ----
        #pragma unroll
        for (int jt = 0; jt < 4; jt++)
            #pragma unroll
            for (int reg = 0; reg < 4; reg++)
                Ps[w * 16 + l4 * 4 + reg][jt * 16 + l15] = (__bf16)sc[jt][reg];
        asm volatile("" ::: "memory");
        bf8 pa0 = *(const bf8*)&Ps[w * 16 + l15][l4 * 8];
        bf8 pa1 = *(const bf8*)&Ps[w * 16 + l15][32 + l4 * 8];
        #pragma unroll
        for (int dt = 0; dt < 4; dt++) {
            bf8 v0 = *(const bf8*)&Vt[dt * 16 + l15][l4 * 8];
            bf8 v1 = *(const bf8*)&Vt[dt * 16 + l15][32 + l4 * 8];
            o[dt] = MFMA16(pa0, v0, o[dt]);
            o[dt] = MFMA16(pa1, v1, o[dt]);
        }
        // ---- qdot for next window's 64 new cols ----
        if (i < 15) {
            #pragma unroll
            for (int jt = 0; jt < 4; jt++) {
                bf8 b0 = *(const bf8*)&Bd[jt * 16 + l15][l4 * 8];
                bf8 b1 = *(const bf8*)&Bd[jt * 16 + l15][32 + l4 * 8];
                f4 f = (f4){0.f, 0.f, 0.f, 0.f};
                f = MFMA16(qa0, b0, f);
                f = MFMA16(qa1, b1, f);
                int j = jlo_next + jt * 16 + l15;
                #pragma unroll
                for (int reg = 0; reg < 4; reg++)
                    Qd[w * 16 + l4 * 4 + reg][j & 127] = (__bf16)f[reg];
            }
        }
        __syncthreads();
    }
    // ---- epilogue ----
    #pragma unroll
    for (int dt = 0; dt < 4; dt++)
        #pragma unroll
        for (int reg = 0; reg < 4; reg++) {
            int srow = s0 + w * 16 + l4 * 4 + reg;
            float v = o[dt][reg] / l_r[reg];
            ctxb[(size_t)(b * SEQ + srow) * DM + h * HD + dt * 16 + l15] = (__bf16)v;
        }
}

// ---------------------------------------------------------------------------
extern "C" void kernel_launch(void* const* d_in, const int* in_sizes, int n_in,
                              void* d_out, int out_size, void* d_ws, size_t ws_size,
                              hipStream_t stream) {
    const float* x    = (const float*)d_in[0];
    // d_in[1] attn_mask: unused by the reference computation
    const float* Wq   = (const float*)d_in[2];
    const float* Wkv  = (const float*)d_in[3];
    const float* Wout = (const float*)d_in[4];
    const float* bout = (const float*)d_in[5];
    const float* pemb = (const float*)d_in[6];
    float* out = (float*)d_out;

    const int M = BATCH * SEQ;   // 4096
    typedef unsigned short u16;
    u16* p = (u16*)d_ws;
    u16* xb    = p; p += (size_t)M * DM;          // 4096x512 (dead after QKV gemm)
    u16* vtb   = xb;                              // aliases xb: 32x64x1024
    u16* qkvw  = p; p += (size_t)NQKV * DM;       // 1536x512 (Wq^T ++ Wkv^T)
    u16* Woutt = p; p += (size_t)DM * DM;         // 512x512
    u16* pembb = p; p += (size_t)1025 * HD;       // 1025x64
    u16* qkv   = p; p += (size_t)M * NQKV;        // 4096x1536
    u16* ctxb  = p; p += (size_t)M * DM;          // 4096x512

    cvt4<<<(M * DM) / 4 / 256, 256, 0, stream>>>(x, xb, M * DM);
    tcvt<<<dim3(16, 16), 256, 0, stream>>>(Wq,   qkvw,            DM, DM);
    tcvt<<<dim3(32, 16), 256, 0, stream>>>(Wkv,  qkvw + DM * DM,  DM, 2 * DM);
    tcvt<<<dim3(16, 16), 256, 0, stream>>>(Wout, Woutt,           DM, DM);
    cvt4<<<(1025 * HD / 4 + 255) / 256, 256, 0, stream>>>(pemb, pembb, 1025 * HD);

    // qkv = x @ [Wq | Wkv]    [4096,1536]
    gemm_bt<<<dim3(NQKV / 128, M / 128), 256, 0, stream>>>(xb, qkvw, M, NQKV, DM,
                                                           (__bf16*)qkv, nullptr, nullptr);
    // V -> [b,h,d,t] (vtb aliases xb, which is dead now)
    vtrans<<<dim3(SEQ / 64, BATCH * NH), 256, 0, stream>>>(qkv, vtb);
    // fused attention -> ctx [4096,512]
    attn_mfma<<<dim3(SEQ / 64, BATCH * NH), 256, 0, stream>>>(qkv, vtb, pembb, (__bf16*)ctxb);
    // out = ctx @ Wout + bout
    gemm_bt<<<dim3(DM / 128, M / 128), 256, 0, stream>>>(ctxb, Woutt, M, DM, DM,
                                                         nullptr, out, bout);
}

// Round 7
// 191.906 us; speedup vs baseline: 10.2032x; 1.0027x over previous
//
#include <hip/hip_runtime.h>
#include <hip/hip_bf16.h>

constexpr int BATCH = 4;
constexpr int SEQ   = 1024;
constexpr int DM    = 512;     // model dim = HEADS*HDIM
constexpr int NH    = 8;
constexpr int HD    = 64;
constexpr int NQKV  = 1536;    // q(512) + k(512) + v(512) fused projection width

typedef unsigned short u16;
typedef __attribute__((ext_vector_type(8))) __bf16 bf8;
typedef __attribute__((ext_vector_type(4))) float  f4;

#define MFMA16(a, b, c) __builtin_amdgcn_mfma_f32_16x16x32_bf16(a, b, c, 0, 0, 0)

static __device__ __forceinline__ u16 f2b(float f) {
    union { float f; unsigned u; } v; v.f = f;
    unsigned r = v.u + 0x7FFFu + ((v.u >> 16) & 1u);   // RNE; inputs never NaN
    return (u16)(r >> 16);
}
static __device__ __forceinline__ float b2f(u16 h) {
    union { unsigned u; float f; } v; v.u = ((unsigned)h) << 16; return v.f;
}
// async global->LDS, 16 B per lane (dst = wave-uniform base + lane*16)
static __device__ __forceinline__ void gl_lds16(const void* g, void* l) {
    __builtin_amdgcn_global_load_lds(
        (const __attribute__((address_space(1))) void*)g,
        (__attribute__((address_space(3))) void*)l, 16, 0, 0);
}

// ---------------------------------------------------------------------------
// Fused prep: one launch does all fp32->bf16 converts + weight transposes.
//   blocks [0,2048)    : cvt x        (4096x512)
//   blocks [2048,2113) : cvt pemb     (1025x64)
//   blocks [2113,2369) : Wq^T  -> qkvw[0]        (512x512)
//   blocks [2369,2881) : Wkv^T -> qkvw[512*512]  (512x1024 -> 1024x512)
//   blocks [2881,3137) : Wout^T -> Woutt         (512x512)
// ---------------------------------------------------------------------------
__device__ __forceinline__ void tcvt_tile(const float* __restrict__ in,
                                          u16* __restrict__ out,
                                          int R, int C, int bx, int by, int tid,
                                          float (*t)[33]) {
    int r0 = by * 32, c0 = bx * 32;
    int lc = tid & 31, lr = tid >> 5;   // lr in [0,8)
    #pragma unroll
    for (int p = 0; p < 4; p++) {
        int r = lr + p * 8;
        t[r][lc] = in[(size_t)(r0 + r) * C + c0 + lc];
    }
    __syncthreads();
    #pragma unroll
    for (int p = 0; p < 4; p++) {
        int r = lr + p * 8;
        out[(size_t)(c0 + r) * R + r0 + lc] = f2b(t[lc][r]);
    }
}

__global__ __launch_bounds__(256)
void prep(const float* __restrict__ x, const float* __restrict__ Wq,
          const float* __restrict__ Wkv, const float* __restrict__ Wout,
          const float* __restrict__ pemb,
          u16* __restrict__ xb, u16* __restrict__ qkvw,
          u16* __restrict__ Woutt, u16* __restrict__ pembb) {
    __shared__ float t[32][33];
    const int blk = blockIdx.x, tid = threadIdx.x;
    if (blk < 2048) {
        int i = (blk * 256 + tid) * 4;
        float4 v = *(const float4*)(x + i);
        ushort4 o = {f2b(v.x), f2b(v.y), f2b(v.z), f2b(v.w)};
        *(ushort4*)(xb + i) = o;
    } else if (blk < 2113) {
        int i = ((blk - 2048) * 256 + tid) * 4;
        if (i < 1025 * HD) {
            float4 v = *(const float4*)(pemb + i);
            ushort4 o = {f2b(v.x), f2b(v.y), f2b(v.z), f2b(v.w)};
            *(ushort4*)(pembb + i) = o;
        }
    } else if (blk < 2369) {
        int l = blk - 2113;
        tcvt_tile(Wq, qkvw, 512, 512, l & 15, l >> 4, tid, t);
    } else if (blk < 2881) {
        int l = blk - 2369;
        tcvt_tile(Wkv, qkvw + 512 * 512, 512, 1024, l & 31, l >> 5, tid, t);
    } else {
        int l = blk - 2881;
        tcvt_tile(Wout, Woutt, 512, 512, l & 15, l >> 4, tid, t);
    }
}

// ---------------------------------------------------------------------------
// V transpose: qkv[4096][1536] cols [1024,1536) -> vtb[(b*8+h)*64+d][1024] (t)
// ---------------------------------------------------------------------------
__global__ __launch_bounds__(256)
void vtrans(const u16* __restrict__ qkv, u16* __restrict__ vtb) {
    __shared__ u16 T[64][66];
    const int tid = threadIdx.x;
    const int t0 = blockIdx.x * 64;
    const int bh = blockIdx.y;             // b*8+h
    const u16* src =
        qkv + (size_t)((bh >> 3) * SEQ + t0) * NQKV + 1024 + (bh & 7) * 64;
    for (int e = tid; e < 4096; e += 256) {
        int t = e >> 6, d = e & 63;
        T[t][d] = src[(size_t)t * NQKV + d];
    }
    __syncthreads();
    u16* dst = vtb + (size_t)bh * 64 * 1024 + t0;
    for (int e = tid; e < 4096; e += 256) {
        int d = e >> 6, t = e & 63;
        dst[(size_t)d * 1024 + t] = T[t][d];
    }
}

// ---------------------------------------------------------------------------
// MFMA GEMM (m97 structure): C[M,N] = A[M,K] @ Bt[N,K]^T   (bf16 in, fp32 acc)
// 128x128 tile, BK=32, 256 threads = 4 waves (2x2), 4x4 16x16x32 frags/wave.
// Staging via global_load_lds width=16 into UNPADDED [128][32] tiles.
// ---------------------------------------------------------------------------
__global__ __launch_bounds__(256)
void gemm_bt(const u16* __restrict__ A, const u16* __restrict__ Bt,
             int M, int N, int K,
             __bf16* __restrict__ Cb, float* __restrict__ Cf,
             const float* __restrict__ bias) {
    __shared__ __align__(16) u16 As[128][32];
    __shared__ __align__(16) u16 Bs[128][32];
    const int tid = threadIdx.x, w = tid >> 6, lane = tid & 63;
    const int l15 = lane & 15, l4 = lane >> 4;
    const int wr = (w >> 1) * 64, wc = (w & 1) * 64;
    const int bm = blockIdx.y * 128, bn = blockIdx.x * 128;

    f4 acc[4][4];
    #pragma unroll
    for (int i = 0; i < 4; i++)
        #pragma unroll
        for (int j = 0; j < 4; j++) acc[i][j] = (f4){0.f, 0.f, 0.f, 0.f};

    const int r0 = (w * 2) * 16 + (lane >> 2);
    const int r1 = (w * 2 + 1) * 16 + (lane >> 2);
    const int cs = (lane & 3) * 8;

    for (int k0 = 0; k0 < K; k0 += 32) {
        gl_lds16(A  + (size_t)(bm + r0) * K + k0 + cs, &As[(w * 2) * 16][0]);
        gl_lds16(A  + (size_t)(bm + r1) * K + k0 + cs, &As[(w * 2 + 1) * 16][0]);
        gl_lds16(Bt + (size_t)(bn + r0) * K + k0 + cs, &Bs[(w * 2) * 16][0]);
        gl_lds16(Bt + (size_t)(bn + r1) * K + k0 + cs, &Bs[(w * 2 + 1) * 16][0]);
        __syncthreads();
        bf8 af[4], bf[4];
        #pragma unroll
        for (int i = 0; i < 4; i++) af[i] = *(const bf8*)&As[wr + i * 16 + l15][l4 * 8];
        #pragma unroll
        for (int j = 0; j < 4; j++) bf[j] = *(const bf8*)&Bs[wc + j * 16 + l15][l4 * 8];
        #pragma unroll
        for (int i = 0; i < 4; i++)
            #pragma unroll
            for (int j = 0; j < 4; j++)
                acc[i][j] = MFMA16(af[i], bf[j], acc[i][j]);
        __syncthreads();
    }
    #pragma unroll
    for (int i = 0; i < 4; i++)
        #pragma unroll
        for (int j = 0; j < 4; j++)
            #pragma unroll
            for (int reg = 0; reg < 4; reg++) {
                int row = bm + wr + i * 16 + l4 * 4 + reg;
                int col = bn + wc + j * 16 + l15;
                float v = acc[i][j][reg];
                if (Cb) Cb[(size_t)row * N + col] = (__bf16)v;
                else    Cf[(size_t)row * N + col] = v + bias[col];
            }
}

// ---------------------------------------------------------------------------
// Fused MFMA flash attention with relative-position term (t-splittable).
// Block = (b,h, 64 q-rows, K-range [istart*64, (istart+iters)*64) ).
// 4 waves, wave w owns q rows [w*16, w*16+16). q pre-scaled by 0.125.
// Sliding 128-col ring Qd[s][j&127] = q_s.pemb[clamp(j)] via MFMA.
// opart!=null -> write unnormalized fp32 partials + (m,l); else write ctx.
// ---------------------------------------------------------------------------
__global__ __launch_bounds__(256)
void attn_mfma(const u16* __restrict__ qkv, const u16* __restrict__ vtb,
               const u16* __restrict__ pembb, __bf16* __restrict__ ctxb,
               int iters, float* __restrict__ opart, float* __restrict__ mlp) {
    __shared__ __align__(16) __bf16 Ks[64][72];   // K tile [t][d]
    __shared__ __align__(16) __bf16 Vt[64][72];   // V tile [d][t] (pre-transposed)
    __shared__ __align__(16) __bf16 Bd[64][72];   // pemb band [r][d]
    __shared__ __align__(16) __bf16 Ps[64][72];   // P tile [s][t] (wave-private rows)
    __shared__ __align__(16) __bf16 Qd[64][136];  // qdot ring [s][j&127]

    const int tid = threadIdx.x, w = tid >> 6, lane = tid & 63;
    const int l15 = lane & 15, l4 = lane >> 4;
    const int bh = blockIdx.y, b = bh >> 3, h = bh & 7;
    const int s0 = blockIdx.x * 64;
    const int istart = blockIdx.z * iters;
    const int iend = istart + iters;

    // Q A-frags (rows w*16+l15, k = l4*8 [+32]), pre-scaled by 2^-3 (exact)
    bf8 qa0, qa1;
    {
        const u16* qp =
            qkv + (size_t)(b * SEQ + s0 + w * 16 + l15) * NQKV + h * HD + l4 * 8;
        union { bf8 v; u16 u[8]; } a0, a1;
        a0.v = *(const bf8*)qp;
        a1.v = *(const bf8*)(qp + 32);
        #pragma unroll
        for (int i = 0; i < 8; i++) {
            a0.u[i] = f2b(b2f(a0.u[i]) * 0.125f);
            a1.u[i] = f2b(b2f(a1.u[i]) * 0.125f);
        }
        qa0 = a0.v; qa1 = a1.v;
    }

    // ---- init ring: window for iter istart = j in [s0+449-64*istart, +127] ----
    #pragma unroll 1
    for (int pass = 0; pass < 2; pass++) {
        const int jlo = s0 + 449 - 64 * istart + pass * 64;
        for (int e = tid; e < 64 * 8; e += 256) {
            int r = e >> 3, c = (e & 7) * 8;
            int jc = min(1024, max(0, jlo + r));
            *(bf8*)&Bd[r][c] = *(const bf8*)(pembb + (size_t)jc * HD + c);
        }
        __syncthreads();
        #pragma unroll
        for (int jt = 0; jt < 4; jt++) {
            bf8 b0 = *(const bf8*)&Bd[jt * 16 + l15][l4 * 8];
            bf8 b1 = *(const bf8*)&Bd[jt * 16 + l15][32 + l4 * 8];
            f4 f = (f4){0.f, 0.f, 0.f, 0.f};
            f = MFMA16(qa0, b0, f);
            f = MFMA16(qa1, b1, f);
            int sl = w * 16 + l4 * 4;
            int j = jlo + jt * 16 + l15;
            #pragma unroll
            for (int reg = 0; reg < 4; reg++)
                Qd[sl + reg][j & 127] = (__bf16)f[reg];
        }
        __syncthreads();
    }

    float m_r[4] = {-1e30f, -1e30f, -1e30f, -1e30f};
    float l_r[4] = {0.f, 0.f, 0.f, 0.f};
    f4 o[4];
    #pragma unroll
    for (int dt = 0; dt < 4; dt++) o[dt] = (f4){0.f, 0.f, 0.f, 0.f};

    const u16* kbase = qkv + (size_t)(b * SEQ) * NQKV + 512 + h * HD;
    const u16* vbase = vtb + (size_t)bh * HD * SEQ;

    for (int i = istart; i < iend; i++) {
        const int t0 = i * 64;
        // ---- staging (vectorized, coalesced) ----
        for (int e = tid; e < 64 * 8; e += 256) {
            int r = e >> 3, c = (e & 7) * 8;
            *(bf8*)&Ks[r][c] = *(const bf8*)(kbase + (size_t)(t0 + r) * NQKV + c);
        }
        for (int e = tid; e < 64 * 8; e += 256) {
            int d = e >> 3, c = (e & 7) * 8;
            *(bf8*)&Vt[d][c] = *(const bf8*)(vbase + (size_t)d * SEQ + t0 + c);
        }
        const int jlo_next = s0 + 449 - 64 * (i + 1);
        if (i + 1 < iend) {
            for (int e = tid; e < 64 * 8; e += 256) {
                int r = e >> 3, c = (e & 7) * 8;
                int jc = min(1024, max(0, jlo_next + r));
                *(bf8*)&Bd[r][c] = *(const bf8*)(pembb + (size_t)jc * HD + c);
            }
        }
        __syncthreads();

        // ---- QK^T (q pre-scaled) ----
        f4 s[4];
        #pragma unroll
        for (int jt = 0; jt < 4; jt++) {
            bf8 b0 = *(const bf8*)&Ks[jt * 16 + l15][l4 * 8];
            bf8 b1 = *(const bf8*)&Ks[jt * 16 + l15][32 + l4 * 8];
            f4 acc = (f4){0.f, 0.f, 0.f, 0.f};
            acc = MFMA16(qa0, b0, acc);
            acc = MFMA16(qa1, b1, acc);
            s[jt] = acc;
        }
        // ---- add pos (ring gather; Qd already scaled via q) ----
        const int jbase = s0 - t0 + 512;
        float sc[4][4];
        #pragma unroll
        for (int jt = 0; jt < 4; jt++) {
            int tl = jt * 16 + l15;
            #pragma unroll
            for (int reg = 0; reg < 4; reg++) {
                int sl = w * 16 + l4 * 4 + reg;
                int j = jbase + sl - tl;
                sc[jt][reg] = s[jt][reg] + (float)Qd[sl][j & 127];
            }
        }
        asm volatile("" ::: "memory");
        // ---- online softmax (stats within 16-lane groups) ----
        float mnew[4], alpha[4];
        #pragma unroll
        for (int reg = 0; reg < 4; reg++) {
            float mx = fmaxf(fmaxf(sc[0][reg], sc[1][reg]), fmaxf(sc[2][reg], sc[3][reg]));
            #pragma unroll
            for (int off = 8; off; off >>= 1) mx = fmaxf(mx, __shfl_xor(mx, off));
            mnew[reg] = fmaxf(m_r[reg], mx);
            alpha[reg] = __expf(m_r[reg] - mnew[reg]);
            m_r[reg] = mnew[reg];
        }
        float rs[4] = {0.f, 0.f, 0.f, 0.f};
        #pragma unroll
        for (int jt = 0; jt < 4; jt++)
            #pragma unroll
            for (int reg = 0; reg < 4; reg++) {
                float p = __expf(sc[jt][reg] - mnew[reg]);
                sc[jt][reg] = p;
                rs[reg] += p;
            }
        #pragma unroll
        for (int reg = 0; reg < 4; reg++) {
            float r2 = rs[reg];
            #pragma unroll
            for (int off = 8; off; off >>= 1) r2 += __shfl_xor(r2, off);
            l_r[reg] = l_r[reg] * alpha[reg] + r2;
        }
        #pragma unroll
        for (int dt = 0; dt < 4; dt++)
            #pragma unroll
            for (int reg = 0; reg < 4; reg++) o[dt][reg] *= alpha[reg];
        // ---- P -> LDS (wave-private rows), then PV ----
        #pragma unroll
        for (int jt = 0; jt < 4; jt++)
            #pragma unroll
            for (int reg = 0; reg < 4; reg++)
                Ps[w * 16 + l4 * 4 + reg][jt * 16 + l15] = (__bf16)sc[jt][reg];
        asm volatile("" ::: "memory");
        bf8 pa0 = *(const bf8*)&Ps[w * 16 + l15][l4 * 8];
        bf8 pa1 = *(const bf8*)&Ps[w * 16 + l15][32 + l4 * 8];
        #pragma unroll
        for (int dt = 0; dt < 4; dt++) {
            bf8 v0 = *(const bf8*)&Vt[dt * 16 + l15][l4 * 8];
            bf8 v1 = *(const bf8*)&Vt[dt * 16 + l15][32 + l4 * 8];
            o[dt] = MFMA16(pa0, v0, o[dt]);
            o[dt] = MFMA16(pa1, v1, o[dt]);
        }
        // ---- qdot for next window's 64 new cols ----
        if (i + 1 < iend) {
            #pragma unroll
            for (int jt = 0; jt < 4; jt++) {
                bf8 b0 = *(const bf8*)&Bd[jt * 16 + l15][l4 * 8];
                bf8 b1 = *(const bf8*)&Bd[jt * 16 + l15][32 + l4 * 8];
                f4 f = (f4){0.f, 0.f, 0.f, 0.f};
                f = MFMA16(qa0, b0, f);
                f = MFMA16(qa1, b1, f);
                int j = jlo_next + jt * 16 + l15;
                #pragma unroll
                for (int reg = 0; reg < 4; reg++)
                    Qd[w * 16 + l4 * 4 + reg][j & 127] = (__bf16)f[reg];
            }
        }
        __syncthreads();
    }
    // ---- epilogue ----
    if (opart) {
        float* ob  = opart + ((((size_t)blockIdx.z * 32 + bh) * 16 + blockIdx.x) * 64) * 64;
        float* mlb = mlp   + (((size_t)blockIdx.z * 32 + bh) * 16 + blockIdx.x) * 128;
        #pragma unroll
        for (int dt = 0; dt < 4; dt++)
            #pragma unroll
            for (int reg = 0; reg < 4; reg++) {
                int sl = w * 16 + l4 * 4 + reg;
                ob[(size_t)sl * 64 + dt * 16 + l15] = o[dt][reg];
            }
        if (l15 == 0) {
            #pragma unroll
            for (int reg = 0; reg < 4; reg++) {
                int sl = w * 16 + l4 * 4 + reg;
                mlb[sl] = m_r[reg];
                mlb[64 + sl] = l_r[reg];
            }
        }
    } else {
        #pragma unroll
        for (int dt = 0; dt < 4; dt++)
            #pragma unroll
            for (int reg = 0; reg < 4; reg++) {
                int srow = s0 + w * 16 + l4 * 4 + reg;
                float v = o[dt][reg] / l_r[reg];
                ctxb[(size_t)(b * SEQ + srow) * DM + h * HD + dt * 16 + l15] = (__bf16)v;
            }
    }
}

// ---------------------------------------------------------------------------
// Combine two t-halves: ctx = (o0*e0 + o1*e1) / (l0*e0 + l1*e1), e=exp(m-mmax)
// ---------------------------------------------------------------------------
__global__ __launch_bounds__(256)
void combine(const float* __restrict__ opart, const float* __restrict__ mlp,
             __bf16* __restrict__ ctxb) {
    __shared__ float f1[64], f2[64];
    const int tid = threadIdx.x;
    const int s0t = blockIdx.x, bh = blockIdx.y;
    const int b = bh >> 3, h = bh & 7;
    const float* ml0 = mlp + (((size_t)0 * 32 + bh) * 16 + s0t) * 128;
    const float* ml1 = mlp + (((size_t)1 * 32 + bh) * 16 + s0t) * 128;
    if (tid < 64) {
        float m1 = ml0[tid], l1 = ml0[64 + tid];
        float m2 = ml1[tid], l2 = ml1[64 + tid];
        float m = fmaxf(m1, m2);
        float e1 = __expf(m1 - m), e2 = __expf(m2 - m);
        float inv = 1.f / (l1 * e1 + l2 * e2);
        f1[tid] = e1 * inv;
        f2[tid] = e2 * inv;
    }
    __syncthreads();
    const float* p0 = opart + ((((size_t)0 * 32 + bh) * 16 + s0t) * 64) * 64;
    const float* p1 = opart + ((((size_t)1 * 32 + bh) * 16 + s0t) * 64) * 64;
    for (int e = tid; e < 4096; e += 256) {
        int s = e >> 6, d = e & 63;
        float v = p0[e] * f1[s] + p1[e] * f2[s];
        int srow = s0t * 64 + s;
        ctxb[(size_t)(b * SEQ + srow) * DM + h * HD + d] = (__bf16)v;
    }
}

// ---------------------------------------------------------------------------
extern "C" void kernel_launch(void* const* d_in, const int* in_sizes, int n_in,
                              void* d_out, int out_size, void* d_ws, size_t ws_size,
                              hipStream_t stream) {
    const float* x    = (const float*)d_in[0];
    // d_in[1] attn_mask: unused by the reference computation
    const float* Wq   = (const float*)d_in[2];
    const float* Wkv  = (const float*)d_in[3];
    const float* Wout = (const float*)d_in[4];
    const float* bout = (const float*)d_in[5];
    const float* pemb = (const float*)d_in[6];
    float* out = (float*)d_out;

    const int M = BATCH * SEQ;   // 4096
    u16* p = (u16*)d_ws;
    u16* xb    = p; p += (size_t)M * DM;          // 4096x512 (dead after QKV gemm)
    u16* vtb   = xb;                              // aliases xb: 32x64x1024
    u16* qkvw  = p; p += (size_t)NQKV * DM;       // 1536x512 (Wq^T ++ Wkv^T)
    u16* Woutt = p; p += (size_t)DM * DM;         // 512x512
    u16* pembb = p; p += (size_t)1025 * HD;       // 1025x64
    u16* qkv   = p; p += (size_t)M * NQKV;        // 4096x1536
    u16* ctxb  = p; p += (size_t)M * DM;          // 4096x512

    // fp32 partials for t-split flash attention (guarded by ws_size)
    size_t off = (size_t)((char*)p - (char*)d_ws);
    off = (off + 15) & ~(size_t)15;
    float* opart = (float*)((char*)d_ws + off);
    const size_t opart_elems = (size_t)2 * 32 * 16 * 64 * 64;   // 4.19M fp32
    const size_t ml_elems    = (size_t)2 * 32 * 16 * 128;
    float* mlp = opart + opart_elems;
    const size_t need = off + (opart_elems + ml_elems) * 4;
    const bool split = ws_size >= need;

    prep<<<3137, 256, 0, stream>>>(x, Wq, Wkv, Wout, pemb, xb, qkvw, Woutt, pembb);

    // qkv = x @ [Wq | Wkv]    [4096,1536]
    gemm_bt<<<dim3(NQKV / 128, M / 128), 256, 0, stream>>>(xb, qkvw, M, NQKV, DM,
                                                           (__bf16*)qkv, nullptr, nullptr);
    // V -> [b,h,d,t] (vtb aliases xb, which is dead now)
    vtrans<<<dim3(SEQ / 64, BATCH * NH), 256, 0, stream>>>(qkv, vtb);

    if (split) {
        attn_mfma<<<dim3(SEQ / 64, BATCH * NH, 2), 256, 0, stream>>>(
            qkv, vtb, pembb, (__bf16*)ctxb, 8, opart, mlp);
        combine<<<dim3(SEQ / 64, BATCH * NH), 256, 0, stream>>>(opart, mlp, (__bf16*)ctxb);
    } else {
        attn_mfma<<<dim3(SEQ / 64, BATCH * NH, 1), 256, 0, stream>>>(
            qkv, vtb, pembb, (__bf16*)ctxb, 16, nullptr, nullptr);
    }
    // out = ctx @ Wout + bout
    gemm_bt<<<dim3(DM / 128, M / 128), 256, 0, stream>>>(ctxb, Woutt, M, DM, DM,
                                                         nullptr, out, bout);
}

// Round 8
// 187.728 us; speedup vs baseline: 10.4302x; 1.0223x over previous
//
#include <hip/hip_runtime.h>
#include <hip/hip_bf16.h>

constexpr int BATCH = 4;
constexpr int SEQ   = 1024;
constexpr int DM    = 512;     // model dim = HEADS*HDIM
constexpr int NH    = 8;
constexpr int HD    = 64;
constexpr int NQKV  = 1536;    // q(512) + k(512) + v(512) fused projection width

typedef unsigned short u16;
typedef __attribute__((ext_vector_type(8))) __bf16 bf8;
typedef __attribute__((ext_vector_type(4))) float  f4;

#define MFMA16(a, b, c) __builtin_amdgcn_mfma_f32_16x16x32_bf16(a, b, c, 0, 0, 0)

static __device__ __forceinline__ u16 f2b(float f) {
    union { float f; unsigned u; } v; v.f = f;
    unsigned r = v.u + 0x7FFFu + ((v.u >> 16) & 1u);   // RNE; inputs never NaN
    return (u16)(r >> 16);
}
static __device__ __forceinline__ float b2f(u16 h) {
    union { unsigned u; float f; } v; v.u = ((unsigned)h) << 16; return v.f;
}
// async global->LDS, 16 B per lane (dst = wave-uniform base + lane*16)
static __device__ __forceinline__ void gl_lds16(const void* g, void* l) {
    __builtin_amdgcn_global_load_lds(
        (const __attribute__((address_space(1))) void*)g,
        (__attribute__((address_space(3))) void*)l, 16, 0, 0);
}

// ---------------------------------------------------------------------------
// Fused prep: one launch does all fp32->bf16 converts + weight transposes.
// ---------------------------------------------------------------------------
__device__ __forceinline__ void tcvt_tile(const float* __restrict__ in,
                                          u16* __restrict__ out,
                                          int R, int C, int bx, int by, int tid,
                                          float (*t)[33]) {
    int r0 = by * 32, c0 = bx * 32;
    int lc = tid & 31, lr = tid >> 5;   // lr in [0,8)
    #pragma unroll
    for (int p = 0; p < 4; p++) {
        int r = lr + p * 8;
        t[r][lc] = in[(size_t)(r0 + r) * C + c0 + lc];
    }
    __syncthreads();
    #pragma unroll
    for (int p = 0; p < 4; p++) {
        int r = lr + p * 8;
        out[(size_t)(c0 + r) * R + r0 + lc] = f2b(t[lc][r]);
    }
}

__global__ __launch_bounds__(256)
void prep(const float* __restrict__ x, const float* __restrict__ Wq,
          const float* __restrict__ Wkv, const float* __restrict__ Wout,
          const float* __restrict__ pemb,
          u16* __restrict__ xb, u16* __restrict__ qkvw,
          u16* __restrict__ Woutt, u16* __restrict__ pembb) {
    __shared__ float t[32][33];
    const int blk = blockIdx.x, tid = threadIdx.x;
    if (blk < 2048) {
        int i = (blk * 256 + tid) * 4;
        float4 v = *(const float4*)(x + i);
        ushort4 o = {f2b(v.x), f2b(v.y), f2b(v.z), f2b(v.w)};
        *(ushort4*)(xb + i) = o;
    } else if (blk < 2113) {
        int i = ((blk - 2048) * 256 + tid) * 4;
        if (i < 1025 * HD) {
            float4 v = *(const float4*)(pemb + i);
            ushort4 o = {f2b(v.x), f2b(v.y), f2b(v.z), f2b(v.w)};
            *(ushort4*)(pembb + i) = o;
        }
    } else if (blk < 2369) {
        int l = blk - 2113;
        tcvt_tile(Wq, qkvw, 512, 512, l & 15, l >> 4, tid, t);
    } else if (blk < 2881) {
        int l = blk - 2369;
        tcvt_tile(Wkv, qkvw + 512 * 512, 512, 1024, l & 31, l >> 5, tid, t);
    } else {
        int l = blk - 2881;
        tcvt_tile(Wout, Woutt, 512, 512, l & 15, l >> 4, tid, t);
    }
}

// ---------------------------------------------------------------------------
// V transpose: qkv[4096][1536] cols [1024,1536) -> vtb[(b*8+h)*64+d][1024] (t)
// ---------------------------------------------------------------------------
__global__ __launch_bounds__(256)
void vtrans(const u16* __restrict__ qkv, u16* __restrict__ vtb) {
    __shared__ u16 T[64][66];
    const int tid = threadIdx.x;
    const int t0 = blockIdx.x * 64;
    const int bh = blockIdx.y;             // b*8+h
    const u16* src =
        qkv + (size_t)((bh >> 3) * SEQ + t0) * NQKV + 1024 + (bh & 7) * 64;
    for (int e = tid; e < 4096; e += 256) {
        int t = e >> 6, d = e & 63;
        T[t][d] = src[(size_t)t * NQKV + d];
    }
    __syncthreads();
    u16* dst = vtb + (size_t)bh * 64 * 1024 + t0;
    for (int e = tid; e < 4096; e += 256) {
        int d = e >> 6, t = e & 63;
        dst[(size_t)d * 1024 + t] = T[t][d];
    }
}

// ---------------------------------------------------------------------------
// MFMA GEMM (m97 structure): C[M,N] = A[M,K] @ Bt[N,K]^T   (bf16 in, fp32 acc)
// ---------------------------------------------------------------------------
__global__ __launch_bounds__(256)
void gemm_bt(const u16* __restrict__ A, const u16* __restrict__ Bt,
             int M, int N, int K,
             __bf16* __restrict__ Cb, float* __restrict__ Cf,
             const float* __restrict__ bias) {
    __shared__ __align__(16) u16 As[128][32];
    __shared__ __align__(16) u16 Bs[128][32];
    const int tid = threadIdx.x, w = tid >> 6, lane = tid & 63;
    const int l15 = lane & 15, l4 = lane >> 4;
    const int wr = (w >> 1) * 64, wc = (w & 1) * 64;
    const int bm = blockIdx.y * 128, bn = blockIdx.x * 128;

    f4 acc[4][4];
    #pragma unroll
    for (int i = 0; i < 4; i++)
        #pragma unroll
        for (int j = 0; j < 4; j++) acc[i][j] = (f4){0.f, 0.f, 0.f, 0.f};

    const int r0 = (w * 2) * 16 + (lane >> 2);
    const int r1 = (w * 2 + 1) * 16 + (lane >> 2);
    const int cs = (lane & 3) * 8;

    for (int k0 = 0; k0 < K; k0 += 32) {
        gl_lds16(A  + (size_t)(bm + r0) * K + k0 + cs, &As[(w * 2) * 16][0]);
        gl_lds16(A  + (size_t)(bm + r1) * K + k0 + cs, &As[(w * 2 + 1) * 16][0]);
        gl_lds16(Bt + (size_t)(bn + r0) * K + k0 + cs, &Bs[(w * 2) * 16][0]);
        gl_lds16(Bt + (size_t)(bn + r1) * K + k0 + cs, &Bs[(w * 2 + 1) * 16][0]);
        __syncthreads();
        bf8 af[4], bf[4];
        #pragma unroll
        for (int i = 0; i < 4; i++) af[i] = *(const bf8*)&As[wr + i * 16 + l15][l4 * 8];
        #pragma unroll
        for (int j = 0; j < 4; j++) bf[j] = *(const bf8*)&Bs[wc + j * 16 + l15][l4 * 8];
        #pragma unroll
        for (int i = 0; i < 4; i++)
            #pragma unroll
            for (int j = 0; j < 4; j++)
                acc[i][j] = MFMA16(af[i], bf[j], acc[i][j]);
        __syncthreads();
    }
    #pragma unroll
    for (int i = 0; i < 4; i++)
        #pragma unroll
        for (int j = 0; j < 4; j++)
            #pragma unroll
            for (int reg = 0; reg < 4; reg++) {
                int row = bm + wr + i * 16 + l4 * 4 + reg;
                int col = bn + wc + j * 16 + l15;
                float v = acc[i][j][reg];
                if (Cb) Cb[(size_t)row * N + col] = (__bf16)v;
                else    Cf[(size_t)row * N + col] = v + bias[col];
            }
}

// ---------------------------------------------------------------------------
// Fused MFMA flash attention with relative-position term (t-splittable).
// LDS = KP(9216) + Vt(9216) + Qd(17408) = 35,840 B -> 4 blocks/CU.
// KP holds the K tile during QK^T, then is reused for the P tile (barrier
// between). pemb B-frags for the qdot ring refresh load straight from global
// (pembb is L2-hot). Qd rows are wave-private: no barriers needed for them.
// ---------------------------------------------------------------------------
__global__ __launch_bounds__(256)
void attn_mfma(const u16* __restrict__ qkv, const u16* __restrict__ vtb,
               const u16* __restrict__ pembb, __bf16* __restrict__ ctxb,
               int iters, float* __restrict__ opart, float* __restrict__ mlp) {
    __shared__ __align__(16) __bf16 KP[64][72];   // K tile [t][d] / P tile [s][t]
    __shared__ __align__(16) __bf16 Vt[64][72];   // V tile [d][t] (pre-transposed)
    __shared__ __align__(16) __bf16 Qd[64][136];  // qdot ring [s][j&127]

    const int tid = threadIdx.x, w = tid >> 6, lane = tid & 63;
    const int l15 = lane & 15, l4 = lane >> 4;
    const int bh = blockIdx.y, b = bh >> 3, h = bh & 7;
    const int s0 = blockIdx.x * 64;
    const int istart = blockIdx.z * iters;
    const int iend = istart + iters;

    // Q A-frags (rows w*16+l15, k = l4*8 [+32]), pre-scaled by 2^-3 (exact)
    bf8 qa0, qa1;
    {
        const u16* qp =
            qkv + (size_t)(b * SEQ + s0 + w * 16 + l15) * NQKV + h * HD + l4 * 8;
        union { bf8 v; u16 u[8]; } a0, a1;
        a0.v = *(const bf8*)qp;
        a1.v = *(const bf8*)(qp + 32);
        #pragma unroll
        for (int i = 0; i < 8; i++) {
            a0.u[i] = f2b(b2f(a0.u[i]) * 0.125f);
            a1.u[i] = f2b(b2f(a1.u[i]) * 0.125f);
        }
        qa0 = a0.v; qa1 = a1.v;
    }

    // ---- init ring: j in [s0+449-64*istart, +127], direct global pemb frags ----
    #pragma unroll
    for (int pass = 0; pass < 2; pass++) {
        const int jlo = s0 + 449 - 64 * istart + pass * 64;
        #pragma unroll
        for (int jt = 0; jt < 4; jt++) {
            int jc = min(1024, max(0, jlo + jt * 16 + l15));
            const u16* pp = pembb + (size_t)jc * HD + l4 * 8;
            bf8 b0 = *(const bf8*)pp;
            bf8 b1 = *(const bf8*)(pp + 32);
            f4 f = (f4){0.f, 0.f, 0.f, 0.f};
            f = MFMA16(qa0, b0, f);
            f = MFMA16(qa1, b1, f);
            int sl = w * 16 + l4 * 4;
            int j = jlo + jt * 16 + l15;
            #pragma unroll
            for (int reg = 0; reg < 4; reg++)
                Qd[sl + reg][j & 127] = (__bf16)f[reg];
        }
    }
    asm volatile("" ::: "memory");

    float m_r[4] = {-1e30f, -1e30f, -1e30f, -1e30f};
    float l_r[4] = {0.f, 0.f, 0.f, 0.f};
    f4 o[4];
    #pragma unroll
    for (int dt = 0; dt < 4; dt++) o[dt] = (f4){0.f, 0.f, 0.f, 0.f};

    const u16* kbase = qkv + (size_t)(b * SEQ) * NQKV + 512 + h * HD;
    const u16* vbase = vtb + (size_t)bh * HD * SEQ;

    for (int i = istart; i < iend; i++) {
        const int t0 = i * 64;
        // ---- stage K and V tiles (vectorized, coalesced) ----
        for (int e = tid; e < 64 * 8; e += 256) {
            int r = e >> 3, c = (e & 7) * 8;
            *(bf8*)&KP[r][c] = *(const bf8*)(kbase + (size_t)(t0 + r) * NQKV + c);
        }
        for (int e = tid; e < 64 * 8; e += 256) {
            int d = e >> 3, c = (e & 7) * 8;
            *(bf8*)&Vt[d][c] = *(const bf8*)(vbase + (size_t)d * SEQ + t0 + c);
        }
        // ---- prefetch pemb frags for the qdot refresh (global, L2-hot) ----
        const int jlo_next = s0 + 449 - 64 * (i + 1);
        const bool do_q = (i + 1 < iend);
        bf8 pb0[4], pb1[4];
        if (do_q) {
            #pragma unroll
            for (int jt = 0; jt < 4; jt++) {
                int jc = min(1024, max(0, jlo_next + jt * 16 + l15));
                const u16* pp = pembb + (size_t)jc * HD + l4 * 8;
                pb0[jt] = *(const bf8*)pp;
                pb1[jt] = *(const bf8*)(pp + 32);
            }
        }
        __syncthreads();

        // ---- QK^T (q pre-scaled) ----
        f4 s[4];
        #pragma unroll
        for (int jt = 0; jt < 4; jt++) {
            bf8 b0 = *(const bf8*)&KP[jt * 16 + l15][l4 * 8];
            bf8 b1 = *(const bf8*)&KP[jt * 16 + l15][32 + l4 * 8];
            f4 acc = (f4){0.f, 0.f, 0.f, 0.f};
            acc = MFMA16(qa0, b0, acc);
            acc = MFMA16(qa1, b1, acc);
            s[jt] = acc;
        }
        // ---- add pos (ring gather; own-wave Qd rows) ----
        const int jbase = s0 - t0 + 512;
        float sc[4][4];
        #pragma unroll
        for (int jt = 0; jt < 4; jt++) {
            int tl = jt * 16 + l15;
            #pragma unroll
            for (int reg = 0; reg < 4; reg++) {
                int sl = w * 16 + l4 * 4 + reg;
                int j = jbase + sl - tl;
                sc[jt][reg] = s[jt][reg] + (float)Qd[sl][j & 127];
            }
        }
        // ---- online softmax (stats within 16-lane groups) ----
        float mnew[4], alpha[4];
        #pragma unroll
        for (int reg = 0; reg < 4; reg++) {
            float mx = fmaxf(fmaxf(sc[0][reg], sc[1][reg]), fmaxf(sc[2][reg], sc[3][reg]));
            #pragma unroll
            for (int off = 8; off; off >>= 1) mx = fmaxf(mx, __shfl_xor(mx, off));
            mnew[reg] = fmaxf(m_r[reg], mx);
            alpha[reg] = __expf(m_r[reg] - mnew[reg]);
            m_r[reg] = mnew[reg];
        }
        float rs[4] = {0.f, 0.f, 0.f, 0.f};
        #pragma unroll
        for (int jt = 0; jt < 4; jt++)
            #pragma unroll
            for (int reg = 0; reg < 4; reg++) {
                float p = __expf(sc[jt][reg] - mnew[reg]);
                sc[jt][reg] = p;
                rs[reg] += p;
            }
        #pragma unroll
        for (int reg = 0; reg < 4; reg++) {
            float r2 = rs[reg];
            #pragma unroll
            for (int off = 8; off; off >>= 1) r2 += __shfl_xor(r2, off);
            l_r[reg] = l_r[reg] * alpha[reg] + r2;
        }
        #pragma unroll
        for (int dt = 0; dt < 4; dt++)
            #pragma unroll
            for (int reg = 0; reg < 4; reg++) o[dt][reg] *= alpha[reg];

        __syncthreads();   // all waves done reading KP as K-tile
        // ---- P -> KP (wave-private rows), then PV ----
        #pragma unroll
        for (int jt = 0; jt < 4; jt++)
            #pragma unroll
            for (int reg = 0; reg < 4; reg++)
                KP[w * 16 + l4 * 4 + reg][jt * 16 + l15] = (__bf16)sc[jt][reg];
        asm volatile("" ::: "memory");
        bf8 pa0 = *(const bf8*)&KP[w * 16 + l15][l4 * 8];
        bf8 pa1 = *(const bf8*)&KP[w * 16 + l15][32 + l4 * 8];
        #pragma unroll
        for (int dt = 0; dt < 4; dt++) {
            bf8 v0 = *(const bf8*)&Vt[dt * 16 + l15][l4 * 8];
            bf8 v1 = *(const bf8*)&Vt[dt * 16 + l15][32 + l4 * 8];
            o[dt] = MFMA16(pa0, v0, o[dt]);
            o[dt] = MFMA16(pa1, v1, o[dt]);
        }
        // ---- qdot for next window's 64 new cols (frags already in regs) ----
        if (do_q) {
            #pragma unroll
            for (int jt = 0; jt < 4; jt++) {
                f4 f = (f4){0.f, 0.f, 0.f, 0.f};
                f = MFMA16(qa0, pb0[jt], f);
                f = MFMA16(qa1, pb1[jt], f);
                int j = jlo_next + jt * 16 + l15;
                #pragma unroll
                for (int reg = 0; reg < 4; reg++)
                    Qd[w * 16 + l4 * 4 + reg][j & 127] = (__bf16)f[reg];
            }
        }
        __syncthreads();   // protect KP/Vt for next iteration's staging
    }
    // ---- epilogue ----
    if (opart) {
        float* ob  = opart + ((((size_t)blockIdx.z * 32 + bh) * 16 + blockIdx.x) * 64) * 64;
        float* mlb = mlp   + (((size_t)blockIdx.z * 32 + bh) * 16 + blockIdx.x) * 128;
        #pragma unroll
        for (int dt = 0; dt < 4; dt++)
            #pragma unroll
            for (int reg = 0; reg < 4; reg++) {
                int sl = w * 16 + l4 * 4 + reg;
                ob[(size_t)sl * 64 + dt * 16 + l15] = o[dt][reg];
            }
        if (l15 == 0) {
            #pragma unroll
            for (int reg = 0; reg < 4; reg++) {
                int sl = w * 16 + l4 * 4 + reg;
                mlb[sl] = m_r[reg];
                mlb[64 + sl] = l_r[reg];
            }
        }
    } else {
        #pragma unroll
        for (int dt = 0; dt < 4; dt++)
            #pragma unroll
            for (int reg = 0; reg < 4; reg++) {
                int srow = s0 + w * 16 + l4 * 4 + reg;
                float v = o[dt][reg] / l_r[reg];
                ctxb[(size_t)(b * SEQ + srow) * DM + h * HD + dt * 16 + l15] = (__bf16)v;
            }
    }
}

// ---------------------------------------------------------------------------
// Combine two t-halves: ctx = (o0*e0 + o1*e1) / (l0*e0 + l1*e1), e=exp(m-mmax)
// ---------------------------------------------------------------------------
__global__ __launch_bounds__(256)
void combine(const float* __restrict__ opart, const float* __restrict__ mlp,
             __bf16* __restrict__ ctxb) {
    __shared__ float f1[64], f2[64];
    const int tid = threadIdx.x;
    const int s0t = blockIdx.x, bh = blockIdx.y;
    const int b = bh >> 3, h = bh & 7;
    const float* ml0 = mlp + (((size_t)0 * 32 + bh) * 16 + s0t) * 128;
    const float* ml1 = mlp + (((size_t)1 * 32 + bh) * 16 + s0t) * 128;
    if (tid < 64) {
        float m1 = ml0[tid], l1 = ml0[64 + tid];
        float m2 = ml1[tid], l2 = ml1[64 + tid];
        float m = fmaxf(m1, m2);
        float e1 = __expf(m1 - m), e2 = __expf(m2 - m);
        float inv = 1.f / (l1 * e1 + l2 * e2);
        f1[tid] = e1 * inv;
        f2[tid] = e2 * inv;
    }
    __syncthreads();
    const float* p0 = opart + ((((size_t)0 * 32 + bh) * 16 + s0t) * 64) * 64;
    const float* p1 = opart + ((((size_t)1 * 32 + bh) * 16 + s0t) * 64) * 64;
    for (int e = tid; e < 4096; e += 256) {
        int s = e >> 6, d = e & 63;
        float v = p0[e] * f1[s] + p1[e] * f2[s];
        int srow = s0t * 64 + s;
        ctxb[(size_t)(b * SEQ + srow) * DM + h * HD + d] = (__bf16)v;
    }
}

// ---------------------------------------------------------------------------
extern "C" void kernel_launch(void* const* d_in, const int* in_sizes, int n_in,
                              void* d_out, int out_size, void* d_ws, size_t ws_size,
                              hipStream_t stream) {
    const float* x    = (const float*)d_in[0];
    // d_in[1] attn_mask: unused by the reference computation
    const float* Wq   = (const float*)d_in[2];
    const float* Wkv  = (const float*)d_in[3];
    const float* Wout = (const float*)d_in[4];
    const float* bout = (const float*)d_in[5];
    const float* pemb = (const float*)d_in[6];
    float* out = (float*)d_out;

    const int M = BATCH * SEQ;   // 4096
    u16* p = (u16*)d_ws;
    u16* xb    = p; p += (size_t)M * DM;          // 4096x512 (dead after QKV gemm)
    u16* vtb   = xb;                              // aliases xb: 32x64x1024
    u16* qkvw  = p; p += (size_t)NQKV * DM;       // 1536x512 (Wq^T ++ Wkv^T)
    u16* Woutt = p; p += (size_t)DM * DM;         // 512x512
    u16* pembb = p; p += (size_t)1025 * HD;       // 1025x64
    u16* qkv   = p; p += (size_t)M * NQKV;        // 4096x1536
    u16* ctxb  = p; p += (size_t)M * DM;          // 4096x512

    // fp32 partials for t-split flash attention (guarded by ws_size)
    size_t off = (size_t)((char*)p - (char*)d_ws);
    off = (off + 15) & ~(size_t)15;
    float* opart = (float*)((char*)d_ws + off);
    const size_t opart_elems = (size_t)2 * 32 * 16 * 64 * 64;   // 4.19M fp32
    const size_t ml_elems    = (size_t)2 * 32 * 16 * 128;
    float* mlp = opart + opart_elems;
    const size_t need = off + (opart_elems + ml_elems) * 4;
    const bool split = ws_size >= need;

    prep<<<3137, 256, 0, stream>>>(x, Wq, Wkv, Wout, pemb, xb, qkvw, Woutt, pembb);

    // qkv = x @ [Wq | Wkv]    [4096,1536]
    gemm_bt<<<dim3(NQKV / 128, M / 128), 256, 0, stream>>>(xb, qkvw, M, NQKV, DM,
                                                           (__bf16*)qkv, nullptr, nullptr);
    // V -> [b,h,d,t] (vtb aliases xb, which is dead now)
    vtrans<<<dim3(SEQ / 64, BATCH * NH), 256, 0, stream>>>(qkv, vtb);

    if (split) {
        attn_mfma<<<dim3(SEQ / 64, BATCH * NH, 2), 256, 0, stream>>>(
            qkv, vtb, pembb, (__bf16*)ctxb, 8, opart, mlp);
        combine<<<dim3(SEQ / 64, BATCH * NH), 256, 0, stream>>>(opart, mlp, (__bf16*)ctxb);
    } else {
        attn_mfma<<<dim3(SEQ / 64, BATCH * NH, 1), 256, 0, stream>>>(
            qkv, vtb, pembb, (__bf16*)ctxb, 16, nullptr, nullptr);
    }
    // out = ctx @ Wout + bout
    gemm_bt<<<dim3(DM / 128, M / 128), 256, 0, stream>>>(ctxb, Woutt, M, DM, DM,
                                                         nullptr, out, bout);
}